// Round 9
// baseline (727.421 us; speedup 1.0000x reference)
//
#include <hip/hip_runtime.h>

typedef unsigned short u16;
typedef __attribute__((ext_vector_type(8))) short bf16x8;
typedef __attribute__((ext_vector_type(4))) float f32x4;

// Problem constants
#define CC   256
#define HH   4
#define HD   64
#define LL   6
#define FCD  1024
#define OUTD 192
#define WSZ  4
#define BB   8
#define TT   1024
#define BT   8192   // B*T

// Output flat offsets (fp32 elements)
#define OFF_XBCT 0
#define OFF_M    2097152
#define OFF_LOGS 3670016
#define OFF_MASK 5242880

// Per-layer bf16 transposed-weight pool layout (u16 elements)
#define WT_Q   0
#define WT_K   65536
#define WT_V   131072
#define WT_O   196608
#define WT_W1  262144
#define WT_W2  524288
#define WT_LAYER 786432
#define WT_TOTAL (6 * WT_LAYER)   // 4,718,592 elems = 9 MB

__device__ __forceinline__ float bf2f(u16 u) {
  union { unsigned int i; float f; } v; v.i = ((unsigned int)u) << 16; return v.f;
}
__device__ __forceinline__ u16 f2bf(float f) {
  union { float f; unsigned int i; } v; v.f = f;
  unsigned int x = v.i;
  return (u16)((x + 0x7fffu + ((x >> 16) & 1u)) >> 16);
}
__device__ __forceinline__ void ldv4(const float* p, float* o) {
  float4 v = *reinterpret_cast<const float4*>(p);
  o[0] = v.x; o[1] = v.y; o[2] = v.z; o[3] = v.w;
}
__device__ __forceinline__ float ld_e(const float* p) { return *p; }
__device__ __forceinline__ float ld_e(const u16* p)   { return bf2f(*p); }
__device__ __forceinline__ void st_e(float* p, float v) { *p = v; }
__device__ __forceinline__ void st_e(u16* p, float v)   { *p = f2bf(v); }

// async global->LDS, 16B per lane (wave-uniform LDS base + lane*16)
__device__ __forceinline__ void gload16(const u16* g, u16* l) {
  __builtin_amdgcn_global_load_lds(
      (const __attribute__((address_space(1))) unsigned int*)g,
      (__attribute__((address_space(3))) unsigned int*)l, 16, 0, 0);
}

// stage 8 contiguous elems of A as bf16 into d[0..7] (legacy path)
__device__ __forceinline__ void stage8(const float* p, u16* d) {
  float4 a = *reinterpret_cast<const float4*>(p);
  float4 b = *reinterpret_cast<const float4*>(p + 4);
  d[0] = f2bf(a.x); d[1] = f2bf(a.y); d[2] = f2bf(a.z); d[3] = f2bf(a.w);
  d[4] = f2bf(b.x); d[5] = f2bf(b.y); d[6] = f2bf(b.z); d[7] = f2bf(b.w);
}
__device__ __forceinline__ void stage8(const u16* p, u16* d) {
  ushort4 a = *reinterpret_cast<const ushort4*>(p);
  ushort4 b = *reinterpret_cast<const ushort4*>(p + 4);
  d[0] = a.x; d[1] = a.y; d[2] = a.z; d[3] = a.w;
  d[4] = b.x; d[5] = b.y; d[6] = b.z; d[7] = b.w;
}
// stage 16 contiguous bf16 elems (32B) via two 16B vector copies
__device__ __forceinline__ void stage16(const u16* src, u16* dst) {
  *reinterpret_cast<bf16x8*>(dst)     = *reinterpret_cast<const bf16x8*>(src);
  *reinterpret_cast<bf16x8*>(dst + 8) = *reinterpret_cast<const bf16x8*>(src + 8);
}

// ---------------- One-time weight transpose-convert: W[k][n] f32 -> WT[n][k] bf16 ----------------
__global__ __launch_bounds__(256) void tc_k(
    const float* __restrict__ W, u16* __restrict__ WT,
    int K, int N, int dstStride)
{
  __shared__ float tl[32][33];
  const int tid = threadIdx.x;
  const int lx = tid & 31;
  const int ly = tid >> 5;           // 0..7
  const int n0 = blockIdx.x << 5;
  const int k0 = blockIdx.y << 5;
  const int z  = blockIdx.z;
  const float* Ws = W + (size_t)z * K * N;
  u16* WTd = WT + (size_t)z * dstStride;
#pragma unroll
  for (int r = 0; r < 4; ++r)
    tl[ly + r * 8][lx] = Ws[(size_t)(k0 + ly + r * 8) * N + (n0 + lx)];
  __syncthreads();
#pragma unroll
  for (int r = 0; r < 4; ++r)
    WTd[(size_t)(n0 + ly + r * 8) * K + (k0 + lx)] = f2bf(tl[lx][ly + r * 8]);
}

// ---------------- Embedding (writes fp32 X and bf16 shadow Xb) ----------------
__global__ __launch_bounds__(256) void embed_k(
    const float* __restrict__ emb, const int* __restrict__ tokens,
    float* __restrict__ X, u16* __restrict__ Xb)
{
  const int i = blockIdx.x * 256 + threadIdx.x;   // BT*CC/4 threads
  const int bt = i >> 6;
  const int c  = (i & 63) << 2;
  float4 e = *reinterpret_cast<const float4*>(emb + (size_t)tokens[bt] * CC + c);
  e.x *= 16.0f; e.y *= 16.0f; e.z *= 16.0f; e.w *= 16.0f;
  *reinterpret_cast<float4*>(X + (size_t)i * 4) = e;
  if (Xb)
    *reinterpret_cast<ushort4*>(Xb + (size_t)i * 4) =
        make_ushort4(f2bf(e.x), f2bf(e.y), f2bf(e.z), f2bf(e.w));
}

// ---------------- MFMA GEMM: 64x64 tile, gload_lds staging ----------------
template <typename CT>
__global__ __launch_bounds__(256) void gemm_t_k(
    const u16* __restrict__ A, int lda, const u16* __restrict__ B, int ldb,
    const float* __restrict__ bias, CT* __restrict__ C, int ldc,
    int K, float ps, int relu, int accum)
{
  __shared__ __align__(16) u16 As[64 * 64];
  __shared__ __align__(16) u16 Bs[64 * 64];
  const int tid  = threadIdx.x;
  const int lane = tid & 63;
  const int wv   = tid >> 6;
  const int bm = blockIdx.y * 64;
  const int bn = blockIdx.x * 64;
  const int l15 = lane & 15;
  const int lq  = lane >> 4;
  const int sb0 = wv << 10;
  const int sb1 = sb0 + 512;
  const int r0  = (wv << 4) + (lane >> 3);
  const int r1  = r0 + 8;
  const int sc  = ((lane & 7) ^ (lane >> 3)) << 3;
  const int asw = (l15 & 7) << 3;

  f32x4 acc[4];
#pragma unroll
  for (int nt = 0; nt < 4; ++nt) acc[nt] = (f32x4){0.0f, 0.0f, 0.0f, 0.0f};

  for (int k0 = 0; k0 < K; k0 += 64) {
    gload16(A + (size_t)(bm + r0) * lda + (k0 + sc), As + sb0);
    gload16(A + (size_t)(bm + r1) * lda + (k0 + sc), As + sb1);
    gload16(B + (size_t)(bn + r0) * ldb + (k0 + sc), Bs + sb0);
    gload16(B + (size_t)(bn + r1) * ldb + (k0 + sc), Bs + sb1);
    __syncthreads();
#pragma unroll
    for (int s = 0; s < 2; ++s) {
      const int cbase = (s << 5) | (lq << 3);
      const bf16x8 af = *reinterpret_cast<const bf16x8*>(
          As + (((wv << 4) + l15) << 6) + (cbase ^ asw));
#pragma unroll
      for (int nt = 0; nt < 4; ++nt) {
        const bf16x8 bf = *reinterpret_cast<const bf16x8*>(
            Bs + (((nt << 4) + l15) << 6) + (cbase ^ asw));
        acc[nt] = __builtin_amdgcn_mfma_f32_16x16x32_bf16(af, bf, acc[nt], 0, 0, 0);
      }
    }
    __syncthreads();
  }

#pragma unroll
  for (int nt = 0; nt < 4; ++nt) {
#pragma unroll
    for (int r = 0; r < 4; ++r) {
      const int row = bm + (wv << 4) + (lq << 2) + r;
      const int col = bn + (nt << 4) + l15;
      float vv = acc[nt][r];
      if (bias) vv += bias[col];
      vv *= ps;
      if (relu) vv = fmaxf(vv, 0.0f);
      const size_t ci = (size_t)row * ldc + col;
      if (accum) vv += ld_e(C + ci);
      st_e(C + ci, vv);
    }
  }
}

// ---------------- MFMA GEMM: 128x128 tile (W1 only — grid must be balanced) ----------------
template <typename CT>
__global__ __launch_bounds__(256) void gemm128_k(
    const u16* __restrict__ A, int lda, const u16* __restrict__ B, int ldb,
    const float* __restrict__ bias, CT* __restrict__ C, int ldc,
    int K, float ps, int relu)
{
  __shared__ __align__(16) u16 As[128 * 64];
  __shared__ __align__(16) u16 Bs[128 * 64];
  const int tid  = threadIdx.x;
  const int lane = tid & 63;
  const int wv   = tid >> 6;
  const int bm = blockIdx.y * 128;
  const int bn = blockIdx.x * 128;
  const int l15 = lane & 15;
  const int lq  = lane >> 4;
  const int wr  = (wv >> 1) << 6;
  const int wc  = (wv & 1) << 6;
  const int rbase = wv << 5;
  const int rlane = lane >> 3;
  const int sc  = ((lane & 7) ^ rlane) << 3;
  const int asw = (l15 & 7) << 3;

  f32x4 acc[4][4];
#pragma unroll
  for (int mf = 0; mf < 4; ++mf)
#pragma unroll
    for (int nf = 0; nf < 4; ++nf) acc[mf][nf] = (f32x4){0.0f, 0.0f, 0.0f, 0.0f};

  for (int k0 = 0; k0 < K; k0 += 64) {
#pragma unroll
    for (int j = 0; j < 4; ++j) {
      gload16(A + (size_t)(bm + rbase + (j << 3) + rlane) * lda + (k0 + sc),
              As + ((rbase + (j << 3)) << 6));
      gload16(B + (size_t)(bn + rbase + (j << 3) + rlane) * ldb + (k0 + sc),
              Bs + ((rbase + (j << 3)) << 6));
    }
    __syncthreads();
#pragma unroll
    for (int s = 0; s < 2; ++s) {
      const int cb = ((s << 5) | (lq << 3)) ^ asw;
      bf16x8 af[4];
#pragma unroll
      for (int mf = 0; mf < 4; ++mf)
        af[mf] = *reinterpret_cast<const bf16x8*>(
            As + ((wr + (mf << 4) + l15) << 6) + cb);
#pragma unroll
      for (int nf = 0; nf < 4; ++nf) {
        const bf16x8 bf = *reinterpret_cast<const bf16x8*>(
            Bs + ((wc + (nf << 4) + l15) << 6) + cb);
#pragma unroll
        for (int mf = 0; mf < 4; ++mf)
          acc[mf][nf] = __builtin_amdgcn_mfma_f32_16x16x32_bf16(af[mf], bf, acc[mf][nf], 0, 0, 0);
      }
    }
    __syncthreads();
  }

#pragma unroll
  for (int mf = 0; mf < 4; ++mf) {
#pragma unroll
    for (int nf = 0; nf < 4; ++nf) {
#pragma unroll
      for (int reg = 0; reg < 4; ++reg) {
        const int row = bm + wr + (mf << 4) + (lq << 2) + reg;
        const int col = bn + wc + (nf << 4) + l15;
        float vv = acc[mf][nf][reg];
        if (bias) vv += bias[col];
        vv *= ps;
        if (relu) vv = fmaxf(vv, 0.0f);
        st_e(C + (size_t)row * ldc + col, vv);
      }
    }
  }
}

// ---------------- Fused QKV GEMM 64x64 (round-7 proven), V stored transposed ----------------
__global__ __launch_bounds__(256) void gemm_qkv_k(
    const u16* __restrict__ Xb, const u16* __restrict__ WTl,
    const float* __restrict__ bq, const float* __restrict__ bk,
    const float* __restrict__ bv,
    u16* __restrict__ Qb, u16* __restrict__ Kb, u16* __restrict__ Vb)
{
  __shared__ __align__(16) u16 pool[2 * 64 * 64];   // As | Bs; V-epilogue reuses as Ts[64][72]
  u16* As = pool;
  u16* Bs = pool + 4096;
  const int tid  = threadIdx.x;
  const int lane = tid & 63;
  const int wv   = tid >> 6;
  const int bx = blockIdx.x;          // 0..11
  const int bm = blockIdx.y * 64;
  const int mi = bx >> 2;             // 0=Q 1=K 2=V
  const int bnl = (bx & 3) << 6;      // col within matrix
  const int bng = bx << 6;            // row in concatenated WT
  const int l15 = lane & 15;
  const int lq  = lane >> 4;
  const int sb0 = wv << 10;
  const int sb1 = sb0 + 512;
  const int r0  = (wv << 4) + (lane >> 3);
  const int r1  = r0 + 8;
  const int sc  = ((lane & 7) ^ (lane >> 3)) << 3;
  const int asw = (l15 & 7) << 3;

  const float* bias = (mi == 0) ? bq : (mi == 1) ? bk : bv;
  const float ps = (mi == 0) ? 0.125f : 1.0f;

  f32x4 acc[4];
#pragma unroll
  for (int nt = 0; nt < 4; ++nt) acc[nt] = (f32x4){0.0f, 0.0f, 0.0f, 0.0f};

  for (int k0 = 0; k0 < CC; k0 += 64) {
    gload16(Xb  + (size_t)(bm + r0) * CC + (k0 + sc), As + sb0);
    gload16(Xb  + (size_t)(bm + r1) * CC + (k0 + sc), As + sb1);
    gload16(WTl + (size_t)(bng + r0) * CC + (k0 + sc), Bs + sb0);
    gload16(WTl + (size_t)(bng + r1) * CC + (k0 + sc), Bs + sb1);
    __syncthreads();
#pragma unroll
    for (int s = 0; s < 2; ++s) {
      const int cbase = (s << 5) | (lq << 3);
      const bf16x8 af = *reinterpret_cast<const bf16x8*>(
          As + (((wv << 4) + l15) << 6) + (cbase ^ asw));
#pragma unroll
      for (int nt = 0; nt < 4; ++nt) {
        const bf16x8 bf = *reinterpret_cast<const bf16x8*>(
            Bs + (((nt << 4) + l15) << 6) + (cbase ^ asw));
        acc[nt] = __builtin_amdgcn_mfma_f32_16x16x32_bf16(af, bf, acc[nt], 0, 0, 0);
      }
    }
    __syncthreads();
  }

  if (mi != 2) {
    u16* Cp = (mi == 0) ? Qb : Kb;
#pragma unroll
    for (int nt = 0; nt < 4; ++nt) {
#pragma unroll
      for (int r = 0; r < 4; ++r) {
        const int row = bm + (wv << 4) + (lq << 2) + r;
        const int col = bnl + (nt << 4) + l15;
        Cp[(size_t)row * CC + col] = f2bf((acc[nt][r] + bias[col]) * ps);
      }
    }
  } else {
    // transpose in LDS, then coalesced stores to VbT[(b*256+col)<<10 | t]
    u16* Ts = pool;   // [64][72]
#pragma unroll
    for (int nt = 0; nt < 4; ++nt) {
#pragma unroll
      for (int r = 0; r < 4; ++r) {
        const int tl = (wv << 4) + (lq << 2) + r;   // local t
        const int dl = (nt << 4) + l15;             // local col
        Ts[dl * 72 + tl] = f2bf(acc[nt][r] + bias[bnl + dl]);
      }
    }
    __syncthreads();
    const int dl = tid >> 2;
    const size_t rowbase =
        ((size_t)((bm >> 10) * 256 + bnl + dl) << 10) + (bm & (TT - 1));
#pragma unroll
    for (int j = 0; j < 4; ++j) {
      const int c4 = ((tid & 3) << 2) + (j << 4);
      *reinterpret_cast<ushort4*>(Vb + rowbase + c4) =
          *reinterpret_cast<const ushort4*>(Ts + dl * 72 + c4);
    }
  }
}

// ---------------- Fused GEMM + residual + LayerNorm ----------------
__global__ __launch_bounds__(256) void gemm_ln_k(
    const u16* __restrict__ A, int lda, const u16* __restrict__ B, int ldb,
    const float* __restrict__ bias,
    float* __restrict__ X, u16* __restrict__ Xb,
    const float* __restrict__ g, const float* __restrict__ be,
    const int* __restrict__ xlen, int am, int K)
{
  __shared__ __align__(16) u16 As[16 * 64];     // 2 KB
  __shared__ __align__(16) u16 Bs[256 * 64];    // 32 KB
  __shared__ float part[16][4];
  __shared__ float part2[16][4];
  const int tid  = threadIdx.x;
  const int lane = tid & 63;
  const int wv   = tid >> 6;          // 0..3
  const int bm   = blockIdx.x << 4;   // 16 rows/block
  const int l15  = lane & 15;
  const int lq   = lane >> 4;
  const int sc   = ((lane & 7) ^ (lane >> 3)) << 3;
  const int asw  = (l15 & 7) << 3;

  f32x4 acc[4];
#pragma unroll
  for (int nt = 0; nt < 4; ++nt) acc[nt] = (f32x4){0.0f, 0.0f, 0.0f, 0.0f};

  for (int k0 = 0; k0 < K; k0 += 64) {
    if (wv < 2)
      gload16(A + (size_t)(bm + (wv << 3) + (lane >> 3)) * lda + (k0 + sc),
              As + (wv << 9));
#pragma unroll
    for (int j = 0; j < 8; ++j)
      gload16(B + (size_t)((wv << 6) + (j << 3) + (lane >> 3)) * ldb + (k0 + sc),
              Bs + (wv << 12) + (j << 9));
    __syncthreads();
#pragma unroll
    for (int s = 0; s < 2; ++s) {
      const int cbase = (s << 5) | (lq << 3);
      const bf16x8 af = *reinterpret_cast<const bf16x8*>(
          As + (l15 << 6) + (cbase ^ asw));
#pragma unroll
      for (int nt = 0; nt < 4; ++nt) {
        const bf16x8 bf = *reinterpret_cast<const bf16x8*>(
            Bs + (((wv << 6) + (nt << 4) + l15) << 6) + (cbase ^ asw));
        acc[nt] = __builtin_amdgcn_mfma_f32_16x16x32_bf16(af, bf, acc[nt], 0, 0, 0);
      }
    }
    __syncthreads();
  }

  float v[4][4];
#pragma unroll
  for (int nt = 0; nt < 4; ++nt) {
    const int col = (wv << 6) + (nt << 4) + l15;
#pragma unroll
    for (int reg = 0; reg < 4; ++reg) {
      const int gr = bm + (lq << 2) + reg;
      v[nt][reg] = acc[nt][reg] + bias[col] + X[(size_t)gr * CC + col];
    }
  }
  float sr[4];
#pragma unroll
  for (int reg = 0; reg < 4; ++reg) {
    float s = v[0][reg] + v[1][reg] + v[2][reg] + v[3][reg];
    s += __shfl_xor(s, 1); s += __shfl_xor(s, 2);
    s += __shfl_xor(s, 4); s += __shfl_xor(s, 8);
    sr[reg] = s;
  }
  if (l15 == 0) {
#pragma unroll
    for (int reg = 0; reg < 4; ++reg) part[(lq << 2) + reg][wv] = sr[reg];
  }
  __syncthreads();
  float mean[4];
#pragma unroll
  for (int reg = 0; reg < 4; ++reg) {
    const int r = (lq << 2) + reg;
    mean[reg] = (part[r][0] + part[r][1] + part[r][2] + part[r][3]) * (1.0f / CC);
  }
#pragma unroll
  for (int reg = 0; reg < 4; ++reg) {
    float s2 = 0.0f;
#pragma unroll
    for (int nt = 0; nt < 4; ++nt) {
      v[nt][reg] -= mean[reg];
      s2 += v[nt][reg] * v[nt][reg];
    }
    s2 += __shfl_xor(s2, 1); s2 += __shfl_xor(s2, 2);
    s2 += __shfl_xor(s2, 4); s2 += __shfl_xor(s2, 8);
    sr[reg] = s2;
  }
  if (l15 == 0) {
#pragma unroll
    for (int reg = 0; reg < 4; ++reg) part2[(lq << 2) + reg][wv] = sr[reg];
  }
  __syncthreads();
#pragma unroll
  for (int reg = 0; reg < 4; ++reg) {
    const int r = (lq << 2) + reg;
    const int gr = bm + r;
    const int b = gr >> 10;
    const int t = gr & (TT - 1);
    const float var = (part2[r][0] + part2[r][1] + part2[r][2] + part2[r][3]) * (1.0f / CC);
    const float rs = rsqrtf(var + 1e-5f);
    const bool zero = (am && t >= xlen[b]);
#pragma unroll
    for (int nt = 0; nt < 4; ++nt) {
      const int col = (wv << 6) + (nt << 4) + l15;
      float y = v[nt][reg] * rs * g[col] + be[col];
      if (zero) y = 0.0f;
      X[(size_t)gr * CC + col] = y;
      Xb[(size_t)gr * CC + col] = f2bf(y);
    }
  }
}

// ---------------- Legacy GEMM (tier-C fallback, fp32 W) ----------------
template <typename AT, typename CT>
__global__ __launch_bounds__(256) void gemm_m_k(
    const AT* __restrict__ A, const float* __restrict__ W, int ldb,
    const float* __restrict__ bias, CT* __restrict__ C, int ldc,
    int K, float ps, int relu, int accum, int vtrans)
{
  __shared__ u16 As[64][40];
  __shared__ u16 Bs[64][40];
  const int tid  = threadIdx.x;
  const int lane = tid & 63;
  const int wv   = tid >> 6;
  const int bm = blockIdx.y * 64;
  const int bn = blockIdx.x * 64;
  const int l15 = lane & 15;
  const int lq  = lane >> 4;
  const int ar = tid >> 2;
  const int ak = (tid & 3) << 3;
  const int kr = tid & 31;
  const int nb = (tid >> 5) << 3;

  f32x4 acc[4];
#pragma unroll
  for (int nt = 0; nt < 4; ++nt) acc[nt] = (f32x4){0.0f, 0.0f, 0.0f, 0.0f};

  for (int k0 = 0; k0 < K; k0 += 32) {
    u16 t8[8];
    stage8(A + (size_t)(bm + ar) * K + (k0 + ak), t8);
    *reinterpret_cast<ushort4*>(&As[ar][ak]) =
        make_ushort4(t8[0], t8[1], t8[2], t8[3]);
    *reinterpret_cast<ushort4*>(&As[ar][ak + 4]) =
        make_ushort4(t8[4], t8[5], t8[6], t8[7]);
    float w8[8];
    ldv4(W + (size_t)(k0 + kr) * ldb + (bn + nb), w8);
    ldv4(W + (size_t)(k0 + kr) * ldb + (bn + nb + 4), w8 + 4);
#pragma unroll
    for (int j = 0; j < 8; ++j) Bs[nb + j][kr] = f2bf(w8[j]);
    __syncthreads();

    const bf16x8 af = *reinterpret_cast<const bf16x8*>(&As[(wv << 4) + l15][lq << 3]);
#pragma unroll
    for (int nt = 0; nt < 4; ++nt) {
      const bf16x8 bf = *reinterpret_cast<const bf16x8*>(&Bs[(nt << 4) + l15][lq << 3]);
      acc[nt] = __builtin_amdgcn_mfma_f32_16x16x32_bf16(af, bf, acc[nt], 0, 0, 0);
    }
    __syncthreads();
  }

#pragma unroll
  for (int nt = 0; nt < 4; ++nt) {
#pragma unroll
    for (int r = 0; r < 4; ++r) {
      const int row = bm + (wv << 4) + (lq << 2) + r;
      const int col = bn + (nt << 4) + l15;
      float vv = acc[nt][r];
      if (bias) vv += bias[col];
      vv *= ps;
      if (relu) vv = fmaxf(vv, 0.0f);
      if (vtrans) {
        const size_t dst = ((size_t)((row >> 10) * 256 + col) << 10) + (row & (TT - 1));
        st_e(C + dst, vv);
      } else {
        const size_t ci = (size_t)row * ldc + col;
        if (accum) vv += ld_e(C + ci);
        st_e(C + ci, vv);
      }
    }
  }
}

// ---------------- Flash attention (round-7 + s_setprio around MFMA clusters) ----------------
#define KLp(g) (KVpool + (g) * 4096)
#define VTp(g) (KVpool + 8192 + (g) * 4096)
__global__ __launch_bounds__(512, 4) void fattn_k(
    const u16* __restrict__ Qb, const u16* __restrict__ Kb,
    const u16* __restrict__ VbT, const float* __restrict__ rk,
    const float* __restrict__ rv, const int* __restrict__ xlen,
    u16* __restrict__ Ob)
{
  __shared__ __align__(16) u16 KVpool[4 * 64 * 64];   // Kl[2] | Vt[2]; merge aliases Oc/mx/lx
  __shared__ u16  Pl[2][64][64];   // Q staged in Pl[0] (unswizzled) during prologue
  __shared__ float rkl[9][64];
  __shared__ float rvl[9][68];
  __shared__ float qrel[64][12];
  __shared__ float bs_s[64][12];
  __shared__ float mrow_s[64];

  const int qt = blockIdx.x;
  const int bh = blockIdx.y;
  const int b  = bh >> 2;
  const int h  = bh & 3;
  const int tid  = threadIdx.x;
  const int lane = tid & 63;
  const int wv   = tid >> 6;       // 0..7
  const int grp  = wv >> 2;        // wave-group 0/1
  const int wvl  = wv & 3;         // wave within group
  const int gtid = tid & 255;      // thread within group
  const int l15  = lane & 15;
  const int lq   = lane >> 4;
  const int len = xlen[b];
  const int q0  = qt << 6;
  const int m0  = wvl << 4;

  if (q0 >= len) {
    for (int i = tid; i < 64 * 16; i += 512) {
      const int r = i >> 4, c4 = (i & 15) << 2;
      *reinterpret_cast<ushort4*>(
          Ob + (size_t)((b << 10) + q0 + r) * CC + (h << 6) + c4) =
          make_ushort4(0, 0, 0, 0);
    }
    return;
  }

  for (int i = tid; i < 9 * 64; i += 512) {
    rkl[i >> 6][i & 63] = rk[i];
    rvl[i >> 6][i & 63] = rv[i];
  }
  for (int i = tid; i < 64 * 16; i += 512) {
    const int r = i >> 4, c4 = (i & 15) << 2;
    *reinterpret_cast<ushort4*>(&Pl[0][r][c4]) = *reinterpret_cast<const ushort4*>(
        Qb + (size_t)((b << 10) + q0 + r) * CC + (h << 6) + c4);
  }
  for (int i = tid; i < 64 * 12; i += 512) (&bs_s[0][0])[i] = -3.0e38f;
  __syncthreads();
  for (int i = tid; i < 64 * 9; i += 512) {
    const int r = i / 9, j = i - r * 9;
    float s = 0.0f;
#pragma unroll 16
    for (int d = 0; d < 64; ++d) s += bf2f(Pl[0][r][d]) * rkl[j][d];
    qrel[r][j] = s;
  }
  __syncthreads();

  const bf16x8 qa0 = *reinterpret_cast<const bf16x8*>(&Pl[0][m0 + l15][lq << 3]);
  const bf16x8 qa1 = *reinterpret_cast<const bf16x8*>(&Pl[0][m0 + l15][32 + (lq << 3)]);

  f32x4 oacc[4];
#pragma unroll
  for (int nt = 0; nt < 4; ++nt) oacc[nt] = (f32x4){0.0f, 0.0f, 0.0f, 0.0f};
  float m_r[4] = {-3.0e38f, -3.0e38f, -3.0e38f, -3.0e38f};
  float l_r[4] = {0.0f, 0.0f, 0.0f, 0.0f};

  const int gr = gtid >> 2;
  const int gc = (gtid & 3) << 4;
  const int rswG = (gr & 7) << 3;
  const int c0w = gc ^ rswG;
  const int c1w = (gc + 8) ^ rswG;
  const int rswF = (l15 & 7) << 3;

  const int nkt = (len + 63) >> 6;
  const int nt0 = (nkt + 1) >> 1;
  const int myBeg = grp ? nt0 : 0;
  const int myEnd = grp ? nkt : nt0;

  u16* klp = KLp(grp);
  u16* vtp = VTp(grp);
  u16* plp = &Pl[grp][0][0];

  bf16x8 kp0, kp1, vq0, vq1;
  if (myBeg < myEnd) {
    const int k0 = myBeg << 6;
    const u16* p = Kb + (size_t)((b << 10) + k0 + gr) * CC + (h << 6) + gc;
    kp0 = *reinterpret_cast<const bf16x8*>(p);
    kp1 = *reinterpret_cast<const bf16x8*>(p + 8);
    const u16* pv = VbT + (size_t)((bh << 6) + gr) * TT + k0 + gc;
    vq0 = *reinterpret_cast<const bf16x8*>(pv);
    vq1 = *reinterpret_cast<const bf16x8*>(pv + 8);
  }

  for (int it = 0; it < nt0; ++it) {
    const int kt = myBeg + it;
    const bool act = (kt < myEnd);
    if (act) {
      *reinterpret_cast<bf16x8*>(klp + gr * 64 + c0w) = kp0;
      *reinterpret_cast<bf16x8*>(klp + gr * 64 + c1w) = kp1;
      *reinterpret_cast<bf16x8*>(vtp + gr * 64 + c0w) = vq0;
      *reinterpret_cast<bf16x8*>(vtp + gr * 64 + c1w) = vq1;
    }
    __syncthreads();

    if (act && kt + 1 < myEnd) {
      const int kn = (kt + 1) << 6;
      const u16* p = Kb + (size_t)((b << 10) + kn + gr) * CC + (h << 6) + gc;
      kp0 = *reinterpret_cast<const bf16x8*>(p);
      kp1 = *reinterpret_cast<const bf16x8*>(p + 8);
      const u16* pv = VbT + (size_t)((bh << 6) + gr) * TT + kn + gc;
      vq0 = *reinterpret_cast<const bf16x8*>(pv);
      vq1 = *reinterpret_cast<const bf16x8*>(pv + 8);
    }

    if (act) {
      const int k0 = kt << 6;
      f32x4 sacc[4];
#pragma unroll
      for (int nt = 0; nt < 4; ++nt) sacc[nt] = (f32x4){0.0f, 0.0f, 0.0f, 0.0f};
      __builtin_amdgcn_s_setprio(1);
#pragma unroll
      for (int nt = 0; nt < 4; ++nt) {
        const int row = (nt << 4) + l15;
        const bf16x8 b0 = *reinterpret_cast<const bf16x8*>(klp + row * 64 + ((lq << 3) ^ rswF));
        const bf16x8 b1 = *reinterpret_cast<const bf16x8*>(klp + row * 64 + ((32 + (lq << 3)) ^ rswF));
        sacc[nt] = __builtin_amdgcn_mfma_f32_16x16x32_bf16(qa0, b0, sacc[nt], 0, 0, 0);
        sacc[nt] = __builtin_amdgcn_mfma_f32_16x16x32_bf16(qa1, b1, sacc[nt], 0, 0, 0);
      }
      __builtin_amdgcn_s_setprio(0);
#pragma unroll
      for (int nt = 0; nt < 4; ++nt) {
#pragma unroll
        for (int reg = 0; reg < 4; ++reg) {
          const int m = m0 + (lq << 2) + reg;
          const int q = q0 + m;
          const int k = k0 + (nt << 4) + l15;
          float s = sacc[nt][reg];
          const int r = k - q;
          const bool band = (r >= -WSZ && r <= WSZ);
          if (band) s += qrel[m][r + WSZ];
          if (q >= len || k >= len) s = -10000.0f;
          if (band) bs_s[m][r + WSZ] = s;
          sacc[nt][reg] = s;
        }
      }
      float aa[4];
#pragma unroll
      for (int reg = 0; reg < 4; ++reg) {
        float mx = fmaxf(fmaxf(sacc[0][reg], sacc[1][reg]),
                         fmaxf(sacc[2][reg], sacc[3][reg]));
        mx = fmaxf(mx, __shfl_xor(mx, 1));
        mx = fmaxf(mx, __shfl_xor(mx, 2));
        mx = fmaxf(mx, __shfl_xor(mx, 4));
        mx = fmaxf(mx, __shfl_xor(mx, 8));
        const float mo = m_r[reg];
        const float mn = fmaxf(mo, mx);
        const float a = __expf(mo - mn);
        m_r[reg] = mn; aa[reg] = a; l_r[reg] *= a;
      }
#pragma unroll
      for (int reg = 0; reg < 4; ++reg) {
        const int m = m0 + (lq << 2) + reg;
        const int msw = (m & 7) << 3;
        const float mn = m_r[reg];
        float ssum = 0.0f;
#pragma unroll
        for (int nt = 0; nt < 4; ++nt) {
          const float p = __expf(sacc[nt][reg] - mn);
          ssum += p;
          plp[m * 64 + (((nt << 4) + l15) ^ msw)] = f2bf(p);
        }
        ssum += __shfl_xor(ssum, 1);
        ssum += __shfl_xor(ssum, 2);
        ssum += __shfl_xor(ssum, 4);
        ssum += __shfl_xor(ssum, 8);
        l_r[reg] += ssum;
      }
#pragma unroll
      for (int nt = 0; nt < 4; ++nt) {
#pragma unroll
        for (int reg = 0; reg < 4; ++reg) oacc[nt][reg] *= aa[reg];
      }
      {
        const int prow = m0 + l15;
        const bf16x8 p0 = *reinterpret_cast<const bf16x8*>(plp + prow * 64 + ((lq << 3) ^ rswF));
        const bf16x8 p1 = *reinterpret_cast<const bf16x8*>(plp + prow * 64 + ((32 + (lq << 3)) ^ rswF));
        __builtin_amdgcn_s_setprio(1);
#pragma unroll
        for (int nt = 0; nt < 4; ++nt) {
          const int row = (nt << 4) + l15;
          const bf16x8 v0 = *reinterpret_cast<const bf16x8*>(vtp + row * 64 + ((lq << 3) ^ rswF));
          const bf16x8 v1 = *reinterpret_cast<const bf16x8*>(vtp + row * 64 + ((32 + (lq << 3)) ^ rswF));
          oacc[nt] = __builtin_amdgcn_mfma_f32_16x16x32_bf16(p0, v0, oacc[nt], 0, 0, 0);
          oacc[nt] = __builtin_amdgcn_mfma_f32_16x16x32_bf16(p1, v1, oacc[nt], 0, 0, 0);
        }
        __builtin_amdgcn_s_setprio(0);
      }
    }
    __syncthreads();
  }

  float* Oc = (float*)KVpool;
  float* mxp = Oc + 64 * 68;
  float* lxp = mxp + 64;
  if (grp == 1) {
#pragma unroll
    for (int nt = 0; nt < 4; ++nt)
#pragma unroll
      for (int reg = 0; reg < 4; ++reg)
        Oc[(m0 + (lq << 2) + reg) * 68 + (nt << 4) + l15] = oacc[nt][reg];
    if (l15 == 0) {
#pragma unroll
      for (int reg = 0; reg < 4; ++reg) {
        mxp[m0 + (lq << 2) + reg] = m_r[reg];
        lxp[m0 + (lq << 2) + reg] = l_r[reg];
      }
    }
  }
  __syncthreads();
  if (grp == 0) {
    float a0c[4], a1c[4];
#pragma unroll
    for (int reg = 0; reg < 4; ++reg) {
      const int m = m0 + (lq << 2) + reg;
      const float m1 = mxp[m], l1 = lxp[m];
      const float mo = m_r[reg];
      const float mn = fmaxf(mo, m1);
      const float a0 = __expf(mo - mn);
      const float a1 = __expf(m1 - mn);
      m_r[reg] = mn;
      l_r[reg] = a0 * l_r[reg] + a1 * l1;
      a0c[reg] = a0; a1c[reg] = a1;
    }
#pragma unroll
    for (int nt = 0; nt < 4; ++nt)
#pragma unroll
      for (int reg = 0; reg < 4; ++reg) {
        const int m = m0 + (lq << 2) + reg;
        oacc[nt][reg] = a0c[reg] * oacc[nt][reg]
                      + a1c[reg] * Oc[m * 68 + (nt << 4) + l15];
      }
    if (l15 == 0) {
#pragma unroll
      for (int reg = 0; reg < 4; ++reg)
        mrow_s[m0 + (lq << 2) + reg] = m_r[reg];
    }
  }
  __syncthreads();
  for (int i = tid; i < 64 * 9; i += 512) {
    const int r = i / 9, j = i - r * 9;
    qrel[r][j] = __expf(bs_s[r][j] - mrow_s[r]);
  }
  __syncthreads();
  if (grp == 0) {
#pragma unroll
    for (int nt = 0; nt < 4; ++nt) {
#pragma unroll
      for (int reg = 0; reg < 4; ++reg) {
        const int m = m0 + (lq << 2) + reg;
        float o = oacc[nt][reg];
#pragma unroll
        for (int j = 0; j < 9; ++j) o += qrel[m][j] * rvl[j][(nt << 4) + l15];
        o *= 1.0f / l_r[reg];
        Ob[(size_t)((b << 10) + q0 + m) * CC + (h << 6) + (nt << 4) + l15] = f2bf(o);
      }
    }
  }
}

// ---------------- Residual add + LayerNorm (tier B/C path) ----------------
__global__ __launch_bounds__(256) void addln_k(
    float* __restrict__ X, u16* __restrict__ Xb, const float* __restrict__ R,
    const float* __restrict__ g, const float* __restrict__ be,
    const int* __restrict__ xlen, int am)
{
  const int tid = threadIdx.x;
  const int row = blockIdx.x * 4 + (tid >> 6);
  const int lane = tid & 63;
  const int b = row >> 10;
  const int t = row & (TT - 1);
  const size_t base = (size_t)row * CC + lane * 4;
  float4 xv = *reinterpret_cast<const float4*>(X + base);
  float4 rv = *reinterpret_cast<const float4*>(R + base);
  float v0 = xv.x + rv.x, v1 = xv.y + rv.y, v2 = xv.z + rv.z, v3 = xv.w + rv.w;
  float s = v0 + v1 + v2 + v3;
#pragma unroll
  for (int off = 32; off > 0; off >>= 1) s += __shfl_xor(s, off);
  const float mean = s * (1.0f / CC);
  const float d0 = v0 - mean, d1 = v1 - mean, d2 = v2 - mean, d3 = v3 - mean;
  float s2 = d0 * d0 + d1 * d1 + d2 * d2 + d3 * d3;
#pragma unroll
  for (int off = 32; off > 0; off >>= 1) s2 += __shfl_xor(s2, off);
  const float rs = rsqrtf(s2 * (1.0f / CC) + 1e-5f);
  const float4 gv = *reinterpret_cast<const float4*>(g + lane * 4);
  const float4 bv = *reinterpret_cast<const float4*>(be + lane * 4);
  float y0 = d0 * rs * gv.x + bv.x;
  float y1 = d1 * rs * gv.y + bv.y;
  float y2 = d2 * rs * gv.z + bv.z;
  float y3 = d3 * rs * gv.w + bv.w;
  if (am && t >= xlen[b]) { y0 = 0.0f; y1 = 0.0f; y2 = 0.0f; y3 = 0.0f; }
  *reinterpret_cast<float4*>(X + base) = make_float4(y0, y1, y2, y3);
  if (Xb)
    *reinterpret_cast<ushort4*>(Xb + base) =
        make_ushort4(f2bf(y0), f2bf(y1), f2bf(y2), f2bf(y3));
}

// ---------------- Final projection -> fp32 m/logs, masked (bf16 MFMA) ----------------
__global__ __launch_bounds__(256) void proj_k(
    const float* __restrict__ A, const float* __restrict__ W,
    const float* __restrict__ bias, const int* __restrict__ xlen,
    float* __restrict__ out)
{
  __shared__ u16 As[64][40];
  __shared__ u16 Bs[64][40];
  const int tid  = threadIdx.x;
  const int lane = tid & 63;
  const int wv   = tid >> 6;
  const int bm = blockIdx.y * 64;
  const int bn = blockIdx.x * 64;
  const int l15 = lane & 15;
  const int lq  = lane >> 4;
  const int ar = tid >> 2;
  const int ak = (tid & 3) << 3;

  f32x4 acc[4];
#pragma unroll
  for (int nt = 0; nt < 4; ++nt) acc[nt] = (f32x4){0.0f, 0.0f, 0.0f, 0.0f};

  for (int k0 = 0; k0 < CC; k0 += 32) {
    u16 t8[8];
    stage8(A + (size_t)(bm + ar) * CC + (k0 + ak), t8);
    *reinterpret_cast<ushort4*>(&As[ar][ak]) =
        make_ushort4(t8[0], t8[1], t8[2], t8[3]);
    *reinterpret_cast<ushort4*>(&As[ar][ak + 4]) =
        make_ushort4(t8[4], t8[5], t8[6], t8[7]);
    stage8(W + (size_t)(bn + ar) * CC + (k0 + ak), t8);
    *reinterpret_cast<ushort4*>(&Bs[ar][ak]) =
        make_ushort4(t8[0], t8[1], t8[2], t8[3]);
    *reinterpret_cast<ushort4*>(&Bs[ar][ak + 4]) =
        make_ushort4(t8[4], t8[5], t8[6], t8[7]);
    __syncthreads();

    const bf16x8 af = *reinterpret_cast<const bf16x8*>(&As[(wv << 4) + l15][lq << 3]);
#pragma unroll
    for (int nt = 0; nt < 4; ++nt) {
      const bf16x8 bf = *reinterpret_cast<const bf16x8*>(&Bs[(nt << 4) + l15][lq << 3]);
      acc[nt] = __builtin_amdgcn_mfma_f32_16x16x32_bf16(af, bf, acc[nt], 0, 0, 0);
    }
    __syncthreads();
  }

#pragma unroll
  for (int nt = 0; nt < 4; ++nt) {
#pragma unroll
    for (int r = 0; r < 4; ++r) {
      const int row = bm + (wv << 4) + (lq << 2) + r;
      const int bb = row >> 10;
      const int t  = row & (TT - 1);
      const int len = xlen[bb];
      const int o = bn + (nt << 4) + l15;
      float vv = acc[nt][r] + bias[o];
      if (t >= len) vv = 0.0f;
      const size_t dst = (o < OUTD)
          ? (size_t)OFF_M    + ((size_t)bb * OUTD + o) * TT + t
          : (size_t)OFF_LOGS + ((size_t)bb * OUTD + (o - OUTD)) * TT + t;
      out[dst] = vv;
    }
  }
}

// ---------------- Output packing: 32x32 LDS tile transpose ----------------
__global__ __launch_bounds__(256) void pack_xbct_k(
    const float* __restrict__ X, float* __restrict__ out)
{
  __shared__ float tl[32][33];
  const int tid = threadIdx.x;
  const int lx = tid & 31;
  const int ly = tid >> 5;            // 0..7
  const int c0 = blockIdx.x << 5;
  const int t0 = blockIdx.y << 5;
  const int b  = blockIdx.z;
#pragma unroll
  for (int r = 0; r < 4; ++r)
    tl[ly + r * 8][lx] = X[(((size_t)(b << 10) + t0 + ly + r * 8) << 8) + c0 + lx];
  __syncthreads();
#pragma unroll
  for (int r = 0; r < 4; ++r)
    out[OFF_XBCT + (((size_t)b * 256 + c0 + ly + r * 8) << 10) + t0 + lx] =
        tl[lx][ly + r * 8];
}

__global__ __launch_bounds__(256) void pack_mask_k(
    const int* __restrict__ xlen, float* __restrict__ out)
{
  const int i = blockIdx.x * 256 + threadIdx.x;
  const int b = i >> 10;
  const int t = i & (TT - 1);
  out[OFF_MASK + i] = (t < xlen[b]) ? 1.0f : 0.0f;
}

extern "C" void kernel_launch(void* const* d_in, const int* in_sizes, int n_in,
                              void* d_out, int out_size, void* d_ws, size_t ws_size,
                              hipStream_t stream)
{
  (void)in_sizes; (void)n_in; (void)out_size;
  const float* emb   = (const float*)d_in[0];
  const float* Wq    = (const float*)d_in[1];
  const float* Wk    = (const float*)d_in[2];
  const float* Wv    = (const float*)d_in[3];
  const float* Wo    = (const float*)d_in[4];
  const float* bq    = (const float*)d_in[5];
  const float* bk    = (const float*)d_in[6];
  const float* bv    = (const float*)d_in[7];
  const float* bo    = (const float*)d_in[8];
  const float* relk  = (const float*)d_in[9];
  const float* relv  = (const float*)d_in[10];
  const float* ln1g  = (const float*)d_in[11];
  const float* ln1b  = (const float*)d_in[12];
  const float* ln2g  = (const float*)d_in[13];
  const float* ln2b  = (const float*)d_in[14];
  const float* W1    = (const float*)d_in[15];
  const float* b1    = (const float*)d_in[16];
  const float* W2    = (const float*)d_in[17];
  const float* b2    = (const float*)d_in[18];
  const float* projw = (const float*)d_in[19];
  const float* projb = (const float*)d_in[20];
  const int*   tokens = (const int*)d_in[21];
  const int*   xlen   = (const int*)d_in[22];
  float* out = (float*)d_out;

  // Workspace tiers (bytes): X 8M | Xb 4M | Wbf 9M | pool
  const size_t TIER_B_WS = 26214400ull;   // X+Xb+Wbf+4M pool (chunked FFN)
  const size_t TIER_A_WS = 38797312ull;   // X+Xb+Wbf+16M pool (full FFN)
  const int tier = (ws_size >= TIER_A_WS) ? 0 : (ws_size >= TIER_B_WS) ? 1 : 2;

  float* X  = (float*)d_ws;
  u16* ObU = (u16*)(out + OFF_XBCT);
  u16* Kb  = (u16*)(out + OFF_M);
  u16* Vb  = (u16*)(out + OFF_LOGS);   // holds VbT (transposed V)
  float* T5 = out + OFF_M;

  if (tier <= 1) {
    u16* Xb  = (u16*)(X + (size_t)BT * CC);
    u16* Wbf = Xb + (size_t)BT * CC;
    u16* pool = Wbf + WT_TOTAL;
    u16* Qb = pool;
    u16* Hc = pool;
    const int CH = (tier == 0) ? 1 : 4;
    const int Wn = FCD / CH;

    // one-time weight transpose-convert
    tc_k<<<dim3(8, 8, 6), 256, 0, stream>>>(Wq, Wbf + WT_Q, CC, CC, WT_LAYER);
    tc_k<<<dim3(8, 8, 6), 256, 0, stream>>>(Wk, Wbf + WT_K, CC, CC, WT_LAYER);
    tc_k<<<dim3(8, 8, 6), 256, 0, stream>>>(Wv, Wbf + WT_V, CC, CC, WT_LAYER);
    tc_k<<<dim3(8, 8, 6), 256, 0, stream>>>(Wo, Wbf + WT_O, CC, CC, WT_LAYER);
    tc_k<<<dim3(32, 8, 6), 256, 0, stream>>>(W1, Wbf + WT_W1, CC, FCD, WT_LAYER);
    tc_k<<<dim3(8, 32, 6), 256, 0, stream>>>(W2, Wbf + WT_W2, FCD, CC, WT_LAYER);

    embed_k<<<(BT * CC / 4) / 256, 256, 0, stream>>>(emb, tokens, X, Xb);

    const dim3 gQKV(12, BT / 64);
    const dim3 gA(16, BB * HH);
    const dim3 gP((2 * OUTD) / 64, BT / 64);

    for (int l = 0; l < LL; ++l) {
      const u16* WTl = Wbf + (size_t)l * WT_LAYER;
      gemm_qkv_k<<<gQKV, 256, 0, stream>>>(Xb, WTl, bq + (size_t)l * CC,
                                           bk + (size_t)l * CC, bv + (size_t)l * CC,
                                           Qb, Kb, Vb);
      fattn_k<<<gA, 512, 0, stream>>>(Qb, Kb, Vb,
                                      relk + (size_t)l * (2 * WSZ + 1) * HD,
                                      relv + (size_t)l * (2 * WSZ + 1) * HD, xlen, ObU);
      // Wo GEMM + residual + LN1 fused
      gemm_ln_k<<<BT / 16, 256, 0, stream>>>(ObU, CC, WTl + WT_O, CC,
                                             bo + (size_t)l * CC, X, Xb,
                                             ln1g + (size_t)l * CC,
                                             ln1b + (size_t)l * CC, xlen, 0, CC);
      if (CH == 1) {
        gemm128_k<u16><<<dim3(FCD / 128, BT / 128), 256, 0, stream>>>(
            Xb, CC, WTl + WT_W1, CC, b1 + (size_t)l * FCD, Hc, FCD, CC,
            1.0f, 1);
        // W2 GEMM + residual + LN2 fused
        gemm_ln_k<<<BT / 16, 256, 0, stream>>>(Hc, FCD, WTl + WT_W2, FCD,
                                               b2 + (size_t)l * CC, X, Xb,
                                               ln2g + (size_t)l * CC,
                                               ln2b + (size_t)l * CC, xlen, 1, FCD);
      } else {
        const dim3 gC(CC / 64, BT / 64);
        for (int c = 0; c < CH; ++c) {
          gemm_t_k<u16><<<dim3(Wn / 64, BT / 64), 256, 0, stream>>>(
              Xb, CC, WTl + WT_W1 + (size_t)c * Wn * CC, CC,
              b1 + (size_t)l * FCD + c * Wn, Hc, Wn, CC, 1.0f, 1, 0);
          gemm_t_k<float><<<gC, 256, 0, stream>>>(
              Hc, Wn, WTl + WT_W2 + (size_t)c * Wn, FCD,
              (c == 0) ? (b2 + (size_t)l * CC) : nullptr, T5, CC, Wn,
              1.0f, 0, (c > 0));
        }
        addln_k<<<BT / 4, 256, 0, stream>>>(X, Xb, T5, ln2g + (size_t)l * CC,
                                            ln2b + (size_t)l * CC, xlen, 1);
      }
    }

    proj_k<<<gP, 256, 0, stream>>>(X, projw, projb, xlen, out);
  } else {
    // Tier C: fallback (fp32 A/W staging), minimal ws
    u16* pool = (u16*)(X + (size_t)BT * CC);
    u16* Qb = pool;
    u16* Hc = pool;

    embed_k<<<(BT * CC / 4) / 256, 256, 0, stream>>>(emb, tokens, X, nullptr);

    const dim3 gC(CC / 64, BT / 64);
    const dim3 gA(16, BB * HH);
    const dim3 gP((2 * OUTD) / 64, BT / 64);

    for (int l = 0; l < LL; ++l) {
      const float* Wq_l = Wq + (size_t)l * CC * CC;
      const float* Wk_l = Wk + (size_t)l * CC * CC;
      const float* Wv_l = Wv + (size_t)l * CC * CC;
      const float* Wo_l = Wo + (size_t)l * CC * CC;

      gemm_m_k<float, u16><<<gC, 256, 0, stream>>>(X, Wq_l, CC, bq + (size_t)l * CC,
                                                   Qb, CC, CC, 0.125f, 0, 0, 0);
      gemm_m_k<float, u16><<<gC, 256, 0, stream>>>(X, Wk_l, CC, bk + (size_t)l * CC,
                                                   Kb, CC, CC, 1.0f, 0, 0, 0);
      gemm_m_k<float, u16><<<gC, 256, 0, stream>>>(X, Wv_l, CC, bv + (size_t)l * CC,
                                                   Vb, CC, CC, 1.0f, 0, 0, 1);
      fattn_k<<<gA, 512, 0, stream>>>(Qb, Kb, Vb,
                                      relk + (size_t)l * (2 * WSZ + 1) * HD,
                                      relv + (size_t)l * (2 * WSZ + 1) * HD, xlen, ObU);
      gemm_m_k<u16, float><<<gC, 256, 0, stream>>>(ObU, Wo_l, CC, bo + (size_t)l * CC,
                                                   T5, CC, CC, 1.0f, 0, 0, 0);
      addln_k<<<BT / 4, 256, 0, stream>>>(X, nullptr, T5, ln1g + (size_t)l * CC,
                                          ln1b + (size_t)l * CC, xlen, 0);
      for (int c = 0; c < 4; ++c) {
        gemm_m_k<float, u16><<<gC, 256, 0, stream>>>(X, W1 + (size_t)l * CC * FCD + c * 256,
                                                     FCD, b1 + (size_t)l * FCD + c * 256,
                                                     Hc, 256, CC, 1.0f, 1, 0, 0);
        gemm_m_k<u16, float><<<gC, 256, 0, stream>>>(Hc,
                                                     W2 + (size_t)l * FCD * CC + (size_t)c * 256 * CC,
                                                     CC, (c == 0) ? (b2 + (size_t)l * CC) : nullptr,
                                                     T5, CC, 256, 1.0f, 0, (c > 0), 0);
      }
      addln_k<<<BT / 4, 256, 0, stream>>>(X, nullptr, T5, ln2g + (size_t)l * CC,
                                          ln2b + (size_t)l * CC, xlen, 1);
    }

    proj_k<<<gP, 256, 0, stream>>>(X, projw, projb, xlen, out);
  }

  pack_xbct_k<<<dim3(CC / 32, TT / 32, BB), 256, 0, stream>>>(X, out);
  pack_mask_k<<<(BB * TT) / 256, 256, 0, stream>>>(xlen, out);
}

// Round 10
// 689.983 us; speedup vs baseline: 1.0543x; 1.0543x over previous
//
#include <hip/hip_runtime.h>

typedef unsigned short u16;
typedef __attribute__((ext_vector_type(8))) short bf16x8;
typedef __attribute__((ext_vector_type(4))) float f32x4;

// Problem constants
#define CC   256
#define HH   4
#define HD   64
#define LL   6
#define FCD  1024
#define OUTD 192
#define WSZ  4
#define BB   8
#define TT   1024
#define BT   8192   // B*T

// Output flat offsets (fp32 elements)
#define OFF_XBCT 0
#define OFF_M    2097152
#define OFF_LOGS 3670016
#define OFF_MASK 5242880

// Per-layer bf16 transposed-weight pool layout (u16 elements)
#define WT_Q   0
#define WT_K   65536
#define WT_V   131072
#define WT_O   196608
#define WT_W1  262144
#define WT_W2  524288
#define WT_LAYER 786432
#define WT_TOTAL (6 * WT_LAYER)   // 4,718,592 elems = 9 MB

__device__ __forceinline__ float bf2f(u16 u) {
  union { unsigned int i; float f; } v; v.i = ((unsigned int)u) << 16; return v.f;
}
__device__ __forceinline__ u16 f2bf(float f) {
  union { float f; unsigned int i; } v; v.f = f;
  unsigned int x = v.i;
  return (u16)((x + 0x7fffu + ((x >> 16) & 1u)) >> 16);
}
__device__ __forceinline__ void ldv4(const float* p, float* o) {
  float4 v = *reinterpret_cast<const float4*>(p);
  o[0] = v.x; o[1] = v.y; o[2] = v.z; o[3] = v.w;
}
__device__ __forceinline__ float ld_e(const float* p) { return *p; }
__device__ __forceinline__ float ld_e(const u16* p)   { return bf2f(*p); }
__device__ __forceinline__ void st_e(float* p, float v) { *p = v; }
__device__ __forceinline__ void st_e(u16* p, float v)   { *p = f2bf(v); }

// async global->LDS, 16B per lane (wave-uniform LDS base + lane*16)
__device__ __forceinline__ void gload16(const u16* g, u16* l) {
  __builtin_amdgcn_global_load_lds(
      (const __attribute__((address_space(1))) unsigned int*)g,
      (__attribute__((address_space(3))) unsigned int*)l, 16, 0, 0);
}

// stage 8 contiguous elems of A as bf16 into d[0..7] (legacy path)
__device__ __forceinline__ void stage8(const float* p, u16* d) {
  float4 a = *reinterpret_cast<const float4*>(p);
  float4 b = *reinterpret_cast<const float4*>(p + 4);
  d[0] = f2bf(a.x); d[1] = f2bf(a.y); d[2] = f2bf(a.z); d[3] = f2bf(a.w);
  d[4] = f2bf(b.x); d[5] = f2bf(b.y); d[6] = f2bf(b.z); d[7] = f2bf(b.w);
}
__device__ __forceinline__ void stage8(const u16* p, u16* d) {
  ushort4 a = *reinterpret_cast<const ushort4*>(p);
  ushort4 b = *reinterpret_cast<const ushort4*>(p + 4);
  d[0] = a.x; d[1] = a.y; d[2] = a.z; d[3] = a.w;
  d[4] = b.x; d[5] = b.y; d[6] = b.z; d[7] = b.w;
}

// ---------------- One-time weight transpose-convert: W[k][n] f32 -> WT[n][k] bf16 ----------------
__global__ __launch_bounds__(256) void tc_k(
    const float* __restrict__ W, u16* __restrict__ WT,
    int K, int N, int dstStride)
{
  __shared__ float tl[32][33];
  const int tid = threadIdx.x;
  const int lx = tid & 31;
  const int ly = tid >> 5;           // 0..7
  const int n0 = blockIdx.x << 5;
  const int k0 = blockIdx.y << 5;
  const int z  = blockIdx.z;
  const float* Ws = W + (size_t)z * K * N;
  u16* WTd = WT + (size_t)z * dstStride;
#pragma unroll
  for (int r = 0; r < 4; ++r)
    tl[ly + r * 8][lx] = Ws[(size_t)(k0 + ly + r * 8) * N + (n0 + lx)];
  __syncthreads();
#pragma unroll
  for (int r = 0; r < 4; ++r)
    WTd[(size_t)(n0 + ly + r * 8) * K + (k0 + lx)] = f2bf(tl[lx][ly + r * 8]);
}

// ---------------- Embedding (writes fp32 X and bf16 shadow Xb) ----------------
__global__ __launch_bounds__(256) void embed_k(
    const float* __restrict__ emb, const int* __restrict__ tokens,
    float* __restrict__ X, u16* __restrict__ Xb)
{
  const int i = blockIdx.x * 256 + threadIdx.x;   // BT*CC/4 threads
  const int bt = i >> 6;
  const int c  = (i & 63) << 2;
  float4 e = *reinterpret_cast<const float4*>(emb + (size_t)tokens[bt] * CC + c);
  e.x *= 16.0f; e.y *= 16.0f; e.z *= 16.0f; e.w *= 16.0f;
  *reinterpret_cast<float4*>(X + (size_t)i * 4) = e;
  if (Xb)
    *reinterpret_cast<ushort4*>(Xb + (size_t)i * 4) =
        make_ushort4(f2bf(e.x), f2bf(e.y), f2bf(e.z), f2bf(e.w));
}

// ---------------- MFMA GEMM: 64x64 tile, gload_lds staging ----------------
template <typename CT>
__global__ __launch_bounds__(256) void gemm_t_k(
    const u16* __restrict__ A, int lda, const u16* __restrict__ B, int ldb,
    const float* __restrict__ bias, CT* __restrict__ C, int ldc,
    int K, float ps, int relu, int accum)
{
  __shared__ __align__(16) u16 As[64 * 64];
  __shared__ __align__(16) u16 Bs[64 * 64];
  const int tid  = threadIdx.x;
  const int lane = tid & 63;
  const int wv   = tid >> 6;
  const int bm = blockIdx.y * 64;
  const int bn = blockIdx.x * 64;
  const int l15 = lane & 15;
  const int lq  = lane >> 4;
  const int sb0 = wv << 10;
  const int sb1 = sb0 + 512;
  const int r0  = (wv << 4) + (lane >> 3);
  const int r1  = r0 + 8;
  const int sc  = ((lane & 7) ^ (lane >> 3)) << 3;
  const int asw = (l15 & 7) << 3;

  f32x4 acc[4];
#pragma unroll
  for (int nt = 0; nt < 4; ++nt) acc[nt] = (f32x4){0.0f, 0.0f, 0.0f, 0.0f};

  for (int k0 = 0; k0 < K; k0 += 64) {
    gload16(A + (size_t)(bm + r0) * lda + (k0 + sc), As + sb0);
    gload16(A + (size_t)(bm + r1) * lda + (k0 + sc), As + sb1);
    gload16(B + (size_t)(bn + r0) * ldb + (k0 + sc), Bs + sb0);
    gload16(B + (size_t)(bn + r1) * ldb + (k0 + sc), Bs + sb1);
    __syncthreads();
#pragma unroll
    for (int s = 0; s < 2; ++s) {
      const int cbase = (s << 5) | (lq << 3);
      const bf16x8 af = *reinterpret_cast<const bf16x8*>(
          As + (((wv << 4) + l15) << 6) + (cbase ^ asw));
#pragma unroll
      for (int nt = 0; nt < 4; ++nt) {
        const bf16x8 bf = *reinterpret_cast<const bf16x8*>(
            Bs + (((nt << 4) + l15) << 6) + (cbase ^ asw));
        acc[nt] = __builtin_amdgcn_mfma_f32_16x16x32_bf16(af, bf, acc[nt], 0, 0, 0);
      }
    }
    __syncthreads();
  }

#pragma unroll
  for (int nt = 0; nt < 4; ++nt) {
#pragma unroll
    for (int r = 0; r < 4; ++r) {
      const int row = bm + (wv << 4) + (lq << 2) + r;
      const int col = bn + (nt << 4) + l15;
      float vv = acc[nt][r];
      if (bias) vv += bias[col];
      vv *= ps;
      if (relu) vv = fmaxf(vv, 0.0f);
      const size_t ci = (size_t)row * ldc + col;
      if (accum) vv += ld_e(C + ci);
      st_e(C + ci, vv);
    }
  }
}

// ---------------- Fused QKV GEMM 64x64, V stored transposed ----------------
__global__ __launch_bounds__(256) void gemm_qkv_k(
    const u16* __restrict__ Xb, const u16* __restrict__ WTl,
    const float* __restrict__ bq, const float* __restrict__ bk,
    const float* __restrict__ bv,
    u16* __restrict__ Qb, u16* __restrict__ Kb, u16* __restrict__ Vb)
{
  __shared__ __align__(16) u16 pool[2 * 64 * 64];   // As | Bs; V-epilogue reuses as Ts[64][72]
  u16* As = pool;
  u16* Bs = pool + 4096;
  const int tid  = threadIdx.x;
  const int lane = tid & 63;
  const int wv   = tid >> 6;
  const int bx = blockIdx.x;          // 0..11
  const int bm = blockIdx.y * 64;
  const int mi = bx >> 2;             // 0=Q 1=K 2=V
  const int bnl = (bx & 3) << 6;      // col within matrix
  const int bng = bx << 6;            // row in concatenated WT
  const int l15 = lane & 15;
  const int lq  = lane >> 4;
  const int sb0 = wv << 10;
  const int sb1 = sb0 + 512;
  const int r0  = (wv << 4) + (lane >> 3);
  const int r1  = r0 + 8;
  const int sc  = ((lane & 7) ^ (lane >> 3)) << 3;
  const int asw = (l15 & 7) << 3;

  const float* bias = (mi == 0) ? bq : (mi == 1) ? bk : bv;
  const float ps = (mi == 0) ? 0.125f : 1.0f;

  f32x4 acc[4];
#pragma unroll
  for (int nt = 0; nt < 4; ++nt) acc[nt] = (f32x4){0.0f, 0.0f, 0.0f, 0.0f};

  for (int k0 = 0; k0 < CC; k0 += 64) {
    gload16(Xb  + (size_t)(bm + r0) * CC + (k0 + sc), As + sb0);
    gload16(Xb  + (size_t)(bm + r1) * CC + (k0 + sc), As + sb1);
    gload16(WTl + (size_t)(bng + r0) * CC + (k0 + sc), Bs + sb0);
    gload16(WTl + (size_t)(bng + r1) * CC + (k0 + sc), Bs + sb1);
    __syncthreads();
#pragma unroll
    for (int s = 0; s < 2; ++s) {
      const int cbase = (s << 5) | (lq << 3);
      const bf16x8 af = *reinterpret_cast<const bf16x8*>(
          As + (((wv << 4) + l15) << 6) + (cbase ^ asw));
#pragma unroll
      for (int nt = 0; nt < 4; ++nt) {
        const bf16x8 bf = *reinterpret_cast<const bf16x8*>(
            Bs + (((nt << 4) + l15) << 6) + (cbase ^ asw));
        acc[nt] = __builtin_amdgcn_mfma_f32_16x16x32_bf16(af, bf, acc[nt], 0, 0, 0);
      }
    }
    __syncthreads();
  }

  if (mi != 2) {
    u16* Cp = (mi == 0) ? Qb : Kb;
#pragma unroll
    for (int nt = 0; nt < 4; ++nt) {
#pragma unroll
      for (int r = 0; r < 4; ++r) {
        const int row = bm + (wv << 4) + (lq << 2) + r;
        const int col = bnl + (nt << 4) + l15;
        Cp[(size_t)row * CC + col] = f2bf((acc[nt][r] + bias[col]) * ps);
      }
    }
  } else {
    u16* Ts = pool;   // [64][72]
#pragma unroll
    for (int nt = 0; nt < 4; ++nt) {
#pragma unroll
      for (int r = 0; r < 4; ++r) {
        const int tl = (wv << 4) + (lq << 2) + r;   // local t
        const int dl = (nt << 4) + l15;             // local col
        Ts[dl * 72 + tl] = f2bf(acc[nt][r] + bias[bnl + dl]);
      }
    }
    __syncthreads();
    const int dl = tid >> 2;
    const size_t rowbase =
        ((size_t)((bm >> 10) * 256 + bnl + dl) << 10) + (bm & (TT - 1));
#pragma unroll
    for (int j = 0; j < 4; ++j) {
      const int c4 = ((tid & 3) << 2) + (j << 4);
      *reinterpret_cast<ushort4*>(Vb + rowbase + c4) =
          *reinterpret_cast<const ushort4*>(Ts + dl * 72 + c4);
    }
  }
}

// ---------------- Fused GEMM + residual + LayerNorm ----------------
__global__ __launch_bounds__(256) void gemm_ln_k(
    const u16* __restrict__ A, int lda, const u16* __restrict__ B, int ldb,
    const float* __restrict__ bias,
    float* __restrict__ X, u16* __restrict__ Xb,
    const float* __restrict__ g, const float* __restrict__ be,
    const int* __restrict__ xlen, int am, int K)
{
  __shared__ __align__(16) u16 As[16 * 64];     // 2 KB
  __shared__ __align__(16) u16 Bs[256 * 64];    // 32 KB
  __shared__ float part[16][4];
  __shared__ float part2[16][4];
  const int tid  = threadIdx.x;
  const int lane = tid & 63;
  const int wv   = tid >> 6;          // 0..3
  const int bm   = blockIdx.x << 4;   // 16 rows/block
  const int l15  = lane & 15;
  const int lq   = lane >> 4;
  const int sc   = ((lane & 7) ^ (lane >> 3)) << 3;
  const int asw  = (l15 & 7) << 3;

  f32x4 acc[4];
#pragma unroll
  for (int nt = 0; nt < 4; ++nt) acc[nt] = (f32x4){0.0f, 0.0f, 0.0f, 0.0f};

  for (int k0 = 0; k0 < K; k0 += 64) {
    if (wv < 2)
      gload16(A + (size_t)(bm + (wv << 3) + (lane >> 3)) * lda + (k0 + sc),
              As + (wv << 9));
#pragma unroll
    for (int j = 0; j < 8; ++j)
      gload16(B + (size_t)((wv << 6) + (j << 3) + (lane >> 3)) * ldb + (k0 + sc),
              Bs + (wv << 12) + (j << 9));
    __syncthreads();
#pragma unroll
    for (int s = 0; s < 2; ++s) {
      const int cbase = (s << 5) | (lq << 3);
      const bf16x8 af = *reinterpret_cast<const bf16x8*>(
          As + (l15 << 6) + (cbase ^ asw));
#pragma unroll
      for (int nt = 0; nt < 4; ++nt) {
        const bf16x8 bf = *reinterpret_cast<const bf16x8*>(
            Bs + (((wv << 6) + (nt << 4) + l15) << 6) + (cbase ^ asw));
        acc[nt] = __builtin_amdgcn_mfma_f32_16x16x32_bf16(af, bf, acc[nt], 0, 0, 0);
      }
    }
    __syncthreads();
  }

  float v[4][4];
#pragma unroll
  for (int nt = 0; nt < 4; ++nt) {
    const int col = (wv << 6) + (nt << 4) + l15;
#pragma unroll
    for (int reg = 0; reg < 4; ++reg) {
      const int gr = bm + (lq << 2) + reg;
      v[nt][reg] = acc[nt][reg] + bias[col] + X[(size_t)gr * CC + col];
    }
  }
  float sr[4];
#pragma unroll
  for (int reg = 0; reg < 4; ++reg) {
    float s = v[0][reg] + v[1][reg] + v[2][reg] + v[3][reg];
    s += __shfl_xor(s, 1); s += __shfl_xor(s, 2);
    s += __shfl_xor(s, 4); s += __shfl_xor(s, 8);
    sr[reg] = s;
  }
  if (l15 == 0) {
#pragma unroll
    for (int reg = 0; reg < 4; ++reg) part[(lq << 2) + reg][wv] = sr[reg];
  }
  __syncthreads();
  float mean[4];
#pragma unroll
  for (int reg = 0; reg < 4; ++reg) {
    const int r = (lq << 2) + reg;
    mean[reg] = (part[r][0] + part[r][1] + part[r][2] + part[r][3]) * (1.0f / CC);
  }
#pragma unroll
  for (int reg = 0; reg < 4; ++reg) {
    float s2 = 0.0f;
#pragma unroll
    for (int nt = 0; nt < 4; ++nt) {
      v[nt][reg] -= mean[reg];
      s2 += v[nt][reg] * v[nt][reg];
    }
    s2 += __shfl_xor(s2, 1); s2 += __shfl_xor(s2, 2);
    s2 += __shfl_xor(s2, 4); s2 += __shfl_xor(s2, 8);
    sr[reg] = s2;
  }
  if (l15 == 0) {
#pragma unroll
    for (int reg = 0; reg < 4; ++reg) part2[(lq << 2) + reg][wv] = sr[reg];
  }
  __syncthreads();
#pragma unroll
  for (int reg = 0; reg < 4; ++reg) {
    const int r = (lq << 2) + reg;
    const int gr = bm + r;
    const int b = gr >> 10;
    const int t = gr & (TT - 1);
    const float var = (part2[r][0] + part2[r][1] + part2[r][2] + part2[r][3]) * (1.0f / CC);
    const float rs = rsqrtf(var + 1e-5f);
    const bool zero = (am && t >= xlen[b]);
#pragma unroll
    for (int nt = 0; nt < 4; ++nt) {
      const int col = (wv << 6) + (nt << 4) + l15;
      float y = v[nt][reg] * rs * g[col] + be[col];
      if (zero) y = 0.0f;
      X[(size_t)gr * CC + col] = y;
      Xb[(size_t)gr * CC + col] = f2bf(y);
    }
  }
}

// ---------------- Legacy GEMM (tier-C fallback, fp32 W) ----------------
template <typename AT, typename CT>
__global__ __launch_bounds__(256) void gemm_m_k(
    const AT* __restrict__ A, const float* __restrict__ W, int ldb,
    const float* __restrict__ bias, CT* __restrict__ C, int ldc,
    int K, float ps, int relu, int accum, int vtrans)
{
  __shared__ u16 As[64][40];
  __shared__ u16 Bs[64][40];
  const int tid  = threadIdx.x;
  const int lane = tid & 63;
  const int wv   = tid >> 6;
  const int bm = blockIdx.y * 64;
  const int bn = blockIdx.x * 64;
  const int l15 = lane & 15;
  const int lq  = lane >> 4;
  const int ar = tid >> 2;
  const int ak = (tid & 3) << 3;
  const int kr = tid & 31;
  const int nb = (tid >> 5) << 3;

  f32x4 acc[4];
#pragma unroll
  for (int nt = 0; nt < 4; ++nt) acc[nt] = (f32x4){0.0f, 0.0f, 0.0f, 0.0f};

  for (int k0 = 0; k0 < K; k0 += 32) {
    u16 t8[8];
    stage8(A + (size_t)(bm + ar) * K + (k0 + ak), t8);
    *reinterpret_cast<ushort4*>(&As[ar][ak]) =
        make_ushort4(t8[0], t8[1], t8[2], t8[3]);
    *reinterpret_cast<ushort4*>(&As[ar][ak + 4]) =
        make_ushort4(t8[4], t8[5], t8[6], t8[7]);
    float w8[8];
    ldv4(W + (size_t)(k0 + kr) * ldb + (bn + nb), w8);
    ldv4(W + (size_t)(k0 + kr) * ldb + (bn + nb + 4), w8 + 4);
#pragma unroll
    for (int j = 0; j < 8; ++j) Bs[nb + j][kr] = f2bf(w8[j]);
    __syncthreads();

    const bf16x8 af = *reinterpret_cast<const bf16x8*>(&As[(wv << 4) + l15][lq << 3]);
#pragma unroll
    for (int nt = 0; nt < 4; ++nt) {
      const bf16x8 bf = *reinterpret_cast<const bf16x8*>(&Bs[(nt << 4) + l15][lq << 3]);
      acc[nt] = __builtin_amdgcn_mfma_f32_16x16x32_bf16(af, bf, acc[nt], 0, 0, 0);
    }
    __syncthreads();
  }

#pragma unroll
  for (int nt = 0; nt < 4; ++nt) {
#pragma unroll
    for (int r = 0; r < 4; ++r) {
      const int row = bm + (wv << 4) + (lq << 2) + r;
      const int col = bn + (nt << 4) + l15;
      float vv = acc[nt][r];
      if (bias) vv += bias[col];
      vv *= ps;
      if (relu) vv = fmaxf(vv, 0.0f);
      if (vtrans) {
        const size_t dst = ((size_t)((row >> 10) * 256 + col) << 10) + (row & (TT - 1));
        st_e(C + dst, vv);
      } else {
        const size_t ci = (size_t)row * ldc + col;
        if (accum) vv += ld_e(C + ci);
        st_e(C + ci, vv);
      }
    }
  }
}

// ---------------- Flash attention (split-K 2 groups + setprio) ----------------
#define KLp(g) (KVpool + (g) * 4096)
#define VTp(g) (KVpool + 8192 + (g) * 4096)
__global__ __launch_bounds__(512, 4) void fattn_k(
    const u16* __restrict__ Qb, const u16* __restrict__ Kb,
    const u16* __restrict__ VbT, const float* __restrict__ rk,
    const float* __restrict__ rv, const int* __restrict__ xlen,
    u16* __restrict__ Ob)
{
  __shared__ __align__(16) u16 KVpool[4 * 64 * 64];
  __shared__ u16  Pl[2][64][64];
  __shared__ float rkl[9][64];
  __shared__ float rvl[9][68];
  __shared__ float qrel[64][12];
  __shared__ float bs_s[64][12];
  __shared__ float mrow_s[64];

  const int qt = blockIdx.x;
  const int bh = blockIdx.y;
  const int b  = bh >> 2;
  const int h  = bh & 3;
  const int tid  = threadIdx.x;
  const int lane = tid & 63;
  const int wv   = tid >> 6;
  const int grp  = wv >> 2;
  const int wvl  = wv & 3;
  const int gtid = tid & 255;
  const int l15  = lane & 15;
  const int lq   = lane >> 4;
  const int len = xlen[b];
  const int q0  = qt << 6;
  const int m0  = wvl << 4;

  if (q0 >= len) {
    for (int i = tid; i < 64 * 16; i += 512) {
      const int r = i >> 4, c4 = (i & 15) << 2;
      *reinterpret_cast<ushort4*>(
          Ob + (size_t)((b << 10) + q0 + r) * CC + (h << 6) + c4) =
          make_ushort4(0, 0, 0, 0);
    }
    return;
  }

  for (int i = tid; i < 9 * 64; i += 512) {
    rkl[i >> 6][i & 63] = rk[i];
    rvl[i >> 6][i & 63] = rv[i];
  }
  for (int i = tid; i < 64 * 16; i += 512) {
    const int r = i >> 4, c4 = (i & 15) << 2;
    *reinterpret_cast<ushort4*>(&Pl[0][r][c4]) = *reinterpret_cast<const ushort4*>(
        Qb + (size_t)((b << 10) + q0 + r) * CC + (h << 6) + c4);
  }
  for (int i = tid; i < 64 * 12; i += 512) (&bs_s[0][0])[i] = -3.0e38f;
  __syncthreads();
  for (int i = tid; i < 64 * 9; i += 512) {
    const int r = i / 9, j = i - r * 9;
    float s = 0.0f;
#pragma unroll 16
    for (int d = 0; d < 64; ++d) s += bf2f(Pl[0][r][d]) * rkl[j][d];
    qrel[r][j] = s;
  }
  __syncthreads();

  const bf16x8 qa0 = *reinterpret_cast<const bf16x8*>(&Pl[0][m0 + l15][lq << 3]);
  const bf16x8 qa1 = *reinterpret_cast<const bf16x8*>(&Pl[0][m0 + l15][32 + (lq << 3)]);

  f32x4 oacc[4];
#pragma unroll
  for (int nt = 0; nt < 4; ++nt) oacc[nt] = (f32x4){0.0f, 0.0f, 0.0f, 0.0f};
  float m_r[4] = {-3.0e38f, -3.0e38f, -3.0e38f, -3.0e38f};
  float l_r[4] = {0.0f, 0.0f, 0.0f, 0.0f};

  const int gr = gtid >> 2;
  const int gc = (gtid & 3) << 4;
  const int rswG = (gr & 7) << 3;
  const int c0w = gc ^ rswG;
  const int c1w = (gc + 8) ^ rswG;
  const int rswF = (l15 & 7) << 3;

  const int nkt = (len + 63) >> 6;
  const int nt0 = (nkt + 1) >> 1;
  const int myBeg = grp ? nt0 : 0;
  const int myEnd = grp ? nkt : nt0;

  u16* klp = KLp(grp);
  u16* vtp = VTp(grp);
  u16* plp = &Pl[grp][0][0];

  bf16x8 kp0, kp1, vq0, vq1;
  if (myBeg < myEnd) {
    const int k0 = myBeg << 6;
    const u16* p = Kb + (size_t)((b << 10) + k0 + gr) * CC + (h << 6) + gc;
    kp0 = *reinterpret_cast<const bf16x8*>(p);
    kp1 = *reinterpret_cast<const bf16x8*>(p + 8);
    const u16* pv = VbT + (size_t)((bh << 6) + gr) * TT + k0 + gc;
    vq0 = *reinterpret_cast<const bf16x8*>(pv);
    vq1 = *reinterpret_cast<const bf16x8*>(pv + 8);
  }

  for (int it = 0; it < nt0; ++it) {
    const int kt = myBeg + it;
    const bool act = (kt < myEnd);
    if (act) {
      *reinterpret_cast<bf16x8*>(klp + gr * 64 + c0w) = kp0;
      *reinterpret_cast<bf16x8*>(klp + gr * 64 + c1w) = kp1;
      *reinterpret_cast<bf16x8*>(vtp + gr * 64 + c0w) = vq0;
      *reinterpret_cast<bf16x8*>(vtp + gr * 64 + c1w) = vq1;
    }
    __syncthreads();

    if (act && kt + 1 < myEnd) {
      const int kn = (kt + 1) << 6;
      const u16* p = Kb + (size_t)((b << 10) + kn + gr) * CC + (h << 6) + gc;
      kp0 = *reinterpret_cast<const bf16x8*>(p);
      kp1 = *reinterpret_cast<const bf16x8*>(p + 8);
      const u16* pv = VbT + (size_t)((bh << 6) + gr) * TT + kn + gc;
      vq0 = *reinterpret_cast<const bf16x8*>(pv);
      vq1 = *reinterpret_cast<const bf16x8*>(pv + 8);
    }

    if (act) {
      const int k0 = kt << 6;
      f32x4 sacc[4];
#pragma unroll
      for (int nt = 0; nt < 4; ++nt) sacc[nt] = (f32x4){0.0f, 0.0f, 0.0f, 0.0f};
      __builtin_amdgcn_s_setprio(1);
#pragma unroll
      for (int nt = 0; nt < 4; ++nt) {
        const int row = (nt << 4) + l15;
        const bf16x8 b0 = *reinterpret_cast<const bf16x8*>(klp + row * 64 + ((lq << 3) ^ rswF));
        const bf16x8 b1 = *reinterpret_cast<const bf16x8*>(klp + row * 64 + ((32 + (lq << 3)) ^ rswF));
        sacc[nt] = __builtin_amdgcn_mfma_f32_16x16x32_bf16(qa0, b0, sacc[nt], 0, 0, 0);
        sacc[nt] = __builtin_amdgcn_mfma_f32_16x16x32_bf16(qa1, b1, sacc[nt], 0, 0, 0);
      }
      __builtin_amdgcn_s_setprio(0);
#pragma unroll
      for (int nt = 0; nt < 4; ++nt) {
#pragma unroll
        for (int reg = 0; reg < 4; ++reg) {
          const int m = m0 + (lq << 2) + reg;
          const int q = q0 + m;
          const int k = k0 + (nt << 4) + l15;
          float s = sacc[nt][reg];
          const int r = k - q;
          const bool band = (r >= -WSZ && r <= WSZ);
          if (band) s += qrel[m][r + WSZ];
          if (q >= len || k >= len) s = -10000.0f;
          if (band) bs_s[m][r + WSZ] = s;
          sacc[nt][reg] = s;
        }
      }
      float aa[4];
#pragma unroll
      for (int reg = 0; reg < 4; ++reg) {
        float mx = fmaxf(fmaxf(sacc[0][reg], sacc[1][reg]),
                         fmaxf(sacc[2][reg], sacc[3][reg]));
        mx = fmaxf(mx, __shfl_xor(mx, 1));
        mx = fmaxf(mx, __shfl_xor(mx, 2));
        mx = fmaxf(mx, __shfl_xor(mx, 4));
        mx = fmaxf(mx, __shfl_xor(mx, 8));
        const float mo = m_r[reg];
        const float mn = fmaxf(mo, mx);
        const float a = __expf(mo - mn);
        m_r[reg] = mn; aa[reg] = a; l_r[reg] *= a;
      }
#pragma unroll
      for (int reg = 0; reg < 4; ++reg) {
        const int m = m0 + (lq << 2) + reg;
        const int msw = (m & 7) << 3;
        const float mn = m_r[reg];
        float ssum = 0.0f;
#pragma unroll
        for (int nt = 0; nt < 4; ++nt) {
          const float p = __expf(sacc[nt][reg] - mn);
          ssum += p;
          plp[m * 64 + (((nt << 4) + l15) ^ msw)] = f2bf(p);
        }
        ssum += __shfl_xor(ssum, 1);
        ssum += __shfl_xor(ssum, 2);
        ssum += __shfl_xor(ssum, 4);
        ssum += __shfl_xor(ssum, 8);
        l_r[reg] += ssum;
      }
#pragma unroll
      for (int nt = 0; nt < 4; ++nt) {
#pragma unroll
        for (int reg = 0; reg < 4; ++reg) oacc[nt][reg] *= aa[reg];
      }
      {
        const int prow = m0 + l15;
        const bf16x8 p0 = *reinterpret_cast<const bf16x8*>(plp + prow * 64 + ((lq << 3) ^ rswF));
        const bf16x8 p1 = *reinterpret_cast<const bf16x8*>(plp + prow * 64 + ((32 + (lq << 3)) ^ rswF));
        __builtin_amdgcn_s_setprio(1);
#pragma unroll
        for (int nt = 0; nt < 4; ++nt) {
          const int row = (nt << 4) + l15;
          const bf16x8 v0 = *reinterpret_cast<const bf16x8*>(vtp + row * 64 + ((lq << 3) ^ rswF));
          const bf16x8 v1 = *reinterpret_cast<const bf16x8*>(vtp + row * 64 + ((32 + (lq << 3)) ^ rswF));
          oacc[nt] = __builtin_amdgcn_mfma_f32_16x16x32_bf16(p0, v0, oacc[nt], 0, 0, 0);
          oacc[nt] = __builtin_amdgcn_mfma_f32_16x16x32_bf16(p1, v1, oacc[nt], 0, 0, 0);
        }
        __builtin_amdgcn_s_setprio(0);
      }
    }
    __syncthreads();
  }

  float* Oc = (float*)KVpool;
  float* mxp = Oc + 64 * 68;
  float* lxp = mxp + 64;
  if (grp == 1) {
#pragma unroll
    for (int nt = 0; nt < 4; ++nt)
#pragma unroll
      for (int reg = 0; reg < 4; ++reg)
        Oc[(m0 + (lq << 2) + reg) * 68 + (nt << 4) + l15] = oacc[nt][reg];
    if (l15 == 0) {
#pragma unroll
      for (int reg = 0; reg < 4; ++reg) {
        mxp[m0 + (lq << 2) + reg] = m_r[reg];
        lxp[m0 + (lq << 2) + reg] = l_r[reg];
      }
    }
  }
  __syncthreads();
  if (grp == 0) {
    float a0c[4], a1c[4];
#pragma unroll
    for (int reg = 0; reg < 4; ++reg) {
      const int m = m0 + (lq << 2) + reg;
      const float m1 = mxp[m], l1 = lxp[m];
      const float mo = m_r[reg];
      const float mn = fmaxf(mo, m1);
      const float a0 = __expf(mo - mn);
      const float a1 = __expf(m1 - mn);
      m_r[reg] = mn;
      l_r[reg] = a0 * l_r[reg] + a1 * l1;
      a0c[reg] = a0; a1c[reg] = a1;
    }
#pragma unroll
    for (int nt = 0; nt < 4; ++nt)
#pragma unroll
      for (int reg = 0; reg < 4; ++reg) {
        const int m = m0 + (lq << 2) + reg;
        oacc[nt][reg] = a0c[reg] * oacc[nt][reg]
                      + a1c[reg] * Oc[m * 68 + (nt << 4) + l15];
      }
    if (l15 == 0) {
#pragma unroll
      for (int reg = 0; reg < 4; ++reg)
        mrow_s[m0 + (lq << 2) + reg] = m_r[reg];
    }
  }
  __syncthreads();
  for (int i = tid; i < 64 * 9; i += 512) {
    const int r = i / 9, j = i - r * 9;
    qrel[r][j] = __expf(bs_s[r][j] - mrow_s[r]);
  }
  __syncthreads();
  if (grp == 0) {
#pragma unroll
    for (int nt = 0; nt < 4; ++nt) {
#pragma unroll
      for (int reg = 0; reg < 4; ++reg) {
        const int m = m0 + (lq << 2) + reg;
        float o = oacc[nt][reg];
#pragma unroll
        for (int j = 0; j < 9; ++j) o += qrel[m][j] * rvl[j][(nt << 4) + l15];
        o *= 1.0f / l_r[reg];
        Ob[(size_t)((b << 10) + q0 + m) * CC + (h << 6) + (nt << 4) + l15] = f2bf(o);
      }
    }
  }
}

// ---------------- Residual add + LayerNorm (tier B/C path) ----------------
__global__ __launch_bounds__(256) void addln_k(
    float* __restrict__ X, u16* __restrict__ Xb, const float* __restrict__ R,
    const float* __restrict__ g, const float* __restrict__ be,
    const int* __restrict__ xlen, int am)
{
  const int tid = threadIdx.x;
  const int row = blockIdx.x * 4 + (tid >> 6);
  const int lane = tid & 63;
  const int b = row >> 10;
  const int t = row & (TT - 1);
  const size_t base = (size_t)row * CC + lane * 4;
  float4 xv = *reinterpret_cast<const float4*>(X + base);
  float4 rv = *reinterpret_cast<const float4*>(R + base);
  float v0 = xv.x + rv.x, v1 = xv.y + rv.y, v2 = xv.z + rv.z, v3 = xv.w + rv.w;
  float s = v0 + v1 + v2 + v3;
#pragma unroll
  for (int off = 32; off > 0; off >>= 1) s += __shfl_xor(s, off);
  const float mean = s * (1.0f / CC);
  const float d0 = v0 - mean, d1 = v1 - mean, d2 = v2 - mean, d3 = v3 - mean;
  float s2 = d0 * d0 + d1 * d1 + d2 * d2 + d3 * d3;
#pragma unroll
  for (int off = 32; off > 0; off >>= 1) s2 += __shfl_xor(s2, off);
  const float rs = rsqrtf(s2 * (1.0f / CC) + 1e-5f);
  const float4 gv = *reinterpret_cast<const float4*>(g + lane * 4);
  const float4 bv = *reinterpret_cast<const float4*>(be + lane * 4);
  float y0 = d0 * rs * gv.x + bv.x;
  float y1 = d1 * rs * gv.y + bv.y;
  float y2 = d2 * rs * gv.z + bv.z;
  float y3 = d3 * rs * gv.w + bv.w;
  if (am && t >= xlen[b]) { y0 = 0.0f; y1 = 0.0f; y2 = 0.0f; y3 = 0.0f; }
  *reinterpret_cast<float4*>(X + base) = make_float4(y0, y1, y2, y3);
  if (Xb)
    *reinterpret_cast<ushort4*>(Xb + base) =
        make_ushort4(f2bf(y0), f2bf(y1), f2bf(y2), f2bf(y3));
}

// ---------------- Final projection -> fp32 m/logs, masked (bf16 MFMA) ----------------
__global__ __launch_bounds__(256) void proj_k(
    const float* __restrict__ A, const float* __restrict__ W,
    const float* __restrict__ bias, const int* __restrict__ xlen,
    float* __restrict__ out)
{
  __shared__ u16 As[64][40];
  __shared__ u16 Bs[64][40];
  const int tid  = threadIdx.x;
  const int lane = tid & 63;
  const int wv   = tid >> 6;
  const int bm = blockIdx.y * 64;
  const int bn = blockIdx.x * 64;
  const int l15 = lane & 15;
  const int lq  = lane >> 4;
  const int ar = tid >> 2;
  const int ak = (tid & 3) << 3;

  f32x4 acc[4];
#pragma unroll
  for (int nt = 0; nt < 4; ++nt) acc[nt] = (f32x4){0.0f, 0.0f, 0.0f, 0.0f};

  for (int k0 = 0; k0 < CC; k0 += 32) {
    u16 t8[8];
    stage8(A + (size_t)(bm + ar) * CC + (k0 + ak), t8);
    *reinterpret_cast<ushort4*>(&As[ar][ak]) =
        make_ushort4(t8[0], t8[1], t8[2], t8[3]);
    *reinterpret_cast<ushort4*>(&As[ar][ak + 4]) =
        make_ushort4(t8[4], t8[5], t8[6], t8[7]);
    stage8(W + (size_t)(bn + ar) * CC + (k0 + ak), t8);
    *reinterpret_cast<ushort4*>(&Bs[ar][ak]) =
        make_ushort4(t8[0], t8[1], t8[2], t8[3]);
    *reinterpret_cast<ushort4*>(&Bs[ar][ak + 4]) =
        make_ushort4(t8[4], t8[5], t8[6], t8[7]);
    __syncthreads();

    const bf16x8 af = *reinterpret_cast<const bf16x8*>(&As[(wv << 4) + l15][lq << 3]);
#pragma unroll
    for (int nt = 0; nt < 4; ++nt) {
      const bf16x8 bf = *reinterpret_cast<const bf16x8*>(&Bs[(nt << 4) + l15][lq << 3]);
      acc[nt] = __builtin_amdgcn_mfma_f32_16x16x32_bf16(af, bf, acc[nt], 0, 0, 0);
    }
    __syncthreads();
  }

#pragma unroll
  for (int nt = 0; nt < 4; ++nt) {
#pragma unroll
    for (int r = 0; r < 4; ++r) {
      const int row = bm + (wv << 4) + (lq << 2) + r;
      const int bb = row >> 10;
      const int t  = row & (TT - 1);
      const int len = xlen[bb];
      const int o = bn + (nt << 4) + l15;
      float vv = acc[nt][r] + bias[o];
      if (t >= len) vv = 0.0f;
      const size_t dst = (o < OUTD)
          ? (size_t)OFF_M    + ((size_t)bb * OUTD + o) * TT + t
          : (size_t)OFF_LOGS + ((size_t)bb * OUTD + (o - OUTD)) * TT + t;
      out[dst] = vv;
    }
  }
}

// ---------------- Output packing: 32x32 LDS tile transpose ----------------
__global__ __launch_bounds__(256) void pack_xbct_k(
    const float* __restrict__ X, float* __restrict__ out)
{
  __shared__ float tl[32][33];
  const int tid = threadIdx.x;
  const int lx = tid & 31;
  const int ly = tid >> 5;            // 0..7
  const int c0 = blockIdx.x << 5;
  const int t0 = blockIdx.y << 5;
  const int b  = blockIdx.z;
#pragma unroll
  for (int r = 0; r < 4; ++r)
    tl[ly + r * 8][lx] = X[(((size_t)(b << 10) + t0 + ly + r * 8) << 8) + c0 + lx];
  __syncthreads();
#pragma unroll
  for (int r = 0; r < 4; ++r)
    out[OFF_XBCT + (((size_t)b * 256 + c0 + ly + r * 8) << 10) + t0 + lx] =
        tl[lx][ly + r * 8];
}

__global__ __launch_bounds__(256) void pack_mask_k(
    const int* __restrict__ xlen, float* __restrict__ out)
{
  const int i = blockIdx.x * 256 + threadIdx.x;
  const int b = i >> 10;
  const int t = i & (TT - 1);
  out[OFF_MASK + i] = (t < xlen[b]) ? 1.0f : 0.0f;
}

extern "C" void kernel_launch(void* const* d_in, const int* in_sizes, int n_in,
                              void* d_out, int out_size, void* d_ws, size_t ws_size,
                              hipStream_t stream)
{
  (void)in_sizes; (void)n_in; (void)out_size;
  const float* emb   = (const float*)d_in[0];
  const float* Wq    = (const float*)d_in[1];
  const float* Wk    = (const float*)d_in[2];
  const float* Wv    = (const float*)d_in[3];
  const float* Wo    = (const float*)d_in[4];
  const float* bq    = (const float*)d_in[5];
  const float* bk    = (const float*)d_in[6];
  const float* bv    = (const float*)d_in[7];
  const float* bo    = (const float*)d_in[8];
  const float* relk  = (const float*)d_in[9];
  const float* relv  = (const float*)d_in[10];
  const float* ln1g  = (const float*)d_in[11];
  const float* ln1b  = (const float*)d_in[12];
  const float* ln2g  = (const float*)d_in[13];
  const float* ln2b  = (const float*)d_in[14];
  const float* W1    = (const float*)d_in[15];
  const float* b1    = (const float*)d_in[16];
  const float* W2    = (const float*)d_in[17];
  const float* b2    = (const float*)d_in[18];
  const float* projw = (const float*)d_in[19];
  const float* projb = (const float*)d_in[20];
  const int*   tokens = (const int*)d_in[21];
  const int*   xlen   = (const int*)d_in[22];
  float* out = (float*)d_out;

  // Workspace tiers (bytes): X 8M | Xb 4M | Wbf 9M | pool
  const size_t TIER_B_WS = 26214400ull;   // X+Xb+Wbf+4M pool (chunked FFN)
  const size_t TIER_A_WS = 38797312ull;   // X+Xb+Wbf+16M pool (full FFN)
  const int tier = (ws_size >= TIER_A_WS) ? 0 : (ws_size >= TIER_B_WS) ? 1 : 2;

  float* X  = (float*)d_ws;
  u16* ObU = (u16*)(out + OFF_XBCT);
  u16* Kb  = (u16*)(out + OFF_M);
  u16* Vb  = (u16*)(out + OFF_LOGS);   // holds VbT (transposed V)
  float* T5 = out + OFF_M;

  if (tier <= 1) {
    u16* Xb  = (u16*)(X + (size_t)BT * CC);
    u16* Wbf = Xb + (size_t)BT * CC;
    u16* pool = Wbf + WT_TOTAL;
    u16* Qb = pool;
    u16* Hc = pool;
    const int CH = (tier == 0) ? 1 : 4;
    const int Wn = FCD / CH;

    // one-time weight transpose-convert
    tc_k<<<dim3(8, 8, 6), 256, 0, stream>>>(Wq, Wbf + WT_Q, CC, CC, WT_LAYER);
    tc_k<<<dim3(8, 8, 6), 256, 0, stream>>>(Wk, Wbf + WT_K, CC, CC, WT_LAYER);
    tc_k<<<dim3(8, 8, 6), 256, 0, stream>>>(Wv, Wbf + WT_V, CC, CC, WT_LAYER);
    tc_k<<<dim3(8, 8, 6), 256, 0, stream>>>(Wo, Wbf + WT_O, CC, CC, WT_LAYER);
    tc_k<<<dim3(32, 8, 6), 256, 0, stream>>>(W1, Wbf + WT_W1, CC, FCD, WT_LAYER);
    tc_k<<<dim3(8, 32, 6), 256, 0, stream>>>(W2, Wbf + WT_W2, FCD, CC, WT_LAYER);

    embed_k<<<(BT * CC / 4) / 256, 256, 0, stream>>>(emb, tokens, X, Xb);

    const dim3 gQKV(12, BT / 64);
    const dim3 gA(16, BB * HH);
    const dim3 gP((2 * OUTD) / 64, BT / 64);

    for (int l = 0; l < LL; ++l) {
      const u16* WTl = Wbf + (size_t)l * WT_LAYER;
      gemm_qkv_k<<<gQKV, 256, 0, stream>>>(Xb, WTl, bq + (size_t)l * CC,
                                           bk + (size_t)l * CC, bv + (size_t)l * CC,
                                           Qb, Kb, Vb);
      fattn_k<<<gA, 512, 0, stream>>>(Qb, Kb, Vb,
                                      relk + (size_t)l * (2 * WSZ + 1) * HD,
                                      relv + (size_t)l * (2 * WSZ + 1) * HD, xlen, ObU);
      // Wo GEMM + residual + LN1 fused
      gemm_ln_k<<<BT / 16, 256, 0, stream>>>(ObU, CC, WTl + WT_O, CC,
                                             bo + (size_t)l * CC, X, Xb,
                                             ln1g + (size_t)l * CC,
                                             ln1b + (size_t)l * CC, xlen, 0, CC);
      if (CH == 1) {
        gemm_t_k<u16><<<dim3(FCD / 64, BT / 64), 256, 0, stream>>>(
            Xb, CC, WTl + WT_W1, CC, b1 + (size_t)l * FCD, Hc, FCD, CC,
            1.0f, 1, 0);
        // W2 GEMM + residual + LN2 fused
        gemm_ln_k<<<BT / 16, 256, 0, stream>>>(Hc, FCD, WTl + WT_W2, FCD,
                                               b2 + (size_t)l * CC, X, Xb,
                                               ln2g + (size_t)l * CC,
                                               ln2b + (size_t)l * CC, xlen, 1, FCD);
      } else {
        const dim3 gC(CC / 64, BT / 64);
        for (int c = 0; c < CH; ++c) {
          gemm_t_k<u16><<<dim3(Wn / 64, BT / 64), 256, 0, stream>>>(
              Xb, CC, WTl + WT_W1 + (size_t)c * Wn * CC, CC,
              b1 + (size_t)l * FCD + c * Wn, Hc, Wn, CC, 1.0f, 1, 0);
          gemm_t_k<float><<<gC, 256, 0, stream>>>(
              Hc, Wn, WTl + WT_W2 + (size_t)c * Wn, FCD,
              (c == 0) ? (b2 + (size_t)l * CC) : nullptr, T5, CC, Wn,
              1.0f, 0, (c > 0));
        }
        addln_k<<<BT / 4, 256, 0, stream>>>(X, Xb, T5, ln2g + (size_t)l * CC,
                                            ln2b + (size_t)l * CC, xlen, 1);
      }
    }

    proj_k<<<gP, 256, 0, stream>>>(X, projw, projb, xlen, out);
  } else {
    // Tier C: fallback (fp32 A/W staging), minimal ws
    u16* pool = (u16*)(X + (size_t)BT * CC);
    u16* Qb = pool;
    u16* Hc = pool;

    embed_k<<<(BT * CC / 4) / 256, 256, 0, stream>>>(emb, tokens, X, nullptr);

    const dim3 gC(CC / 64, BT / 64);
    const dim3 gA(16, BB * HH);
    const dim3 gP((2 * OUTD) / 64, BT / 64);

    for (int l = 0; l < LL; ++l) {
      const float* Wq_l = Wq + (size_t)l * CC * CC;
      const float* Wk_l = Wk + (size_t)l * CC * CC;
      const float* Wv_l = Wv + (size_t)l * CC * CC;
      const float* Wo_l = Wo + (size_t)l * CC * CC;

      gemm_m_k<float, u16><<<gC, 256, 0, stream>>>(X, Wq_l, CC, bq + (size_t)l * CC,
                                                   Qb, CC, CC, 0.125f, 0, 0, 0);
      gemm_m_k<float, u16><<<gC, 256, 0, stream>>>(X, Wk_l, CC, bk + (size_t)l * CC,
                                                   Kb, CC, CC, 1.0f, 0, 0, 0);
      gemm_m_k<float, u16><<<gC, 256, 0, stream>>>(X, Wv_l, CC, bv + (size_t)l * CC,
                                                   Vb, CC, CC, 1.0f, 0, 0, 1);
      fattn_k<<<gA, 512, 0, stream>>>(Qb, Kb, Vb,
                                      relk + (size_t)l * (2 * WSZ + 1) * HD,
                                      relv + (size_t)l * (2 * WSZ + 1) * HD, xlen, ObU);
      gemm_m_k<u16, float><<<gC, 256, 0, stream>>>(ObU, Wo_l, CC, bo + (size_t)l * CC,
                                                   T5, CC, CC, 1.0f, 0, 0, 0);
      addln_k<<<BT / 4, 256, 0, stream>>>(X, nullptr, T5, ln1g + (size_t)l * CC,
                                          ln1b + (size_t)l * CC, xlen, 0);
      for (int c = 0; c < 4; ++c) {
        gemm_m_k<float, u16><<<gC, 256, 0, stream>>>(X, W1 + (size_t)l * CC * FCD + c * 256,
                                                     FCD, b1 + (size_t)l * FCD + c * 256,
                                                     Hc, 256, CC, 1.0f, 1, 0, 0);
        gemm_m_k<u16, float><<<gC, 256, 0, stream>>>(Hc,
                                                     W2 + (size_t)l * FCD * CC + (size_t)c * 256 * CC,
                                                     CC, (c == 0) ? (b2 + (size_t)l * CC) : nullptr,
                                                     T5, CC, 256, 1.0f, 0, (c > 0), 0);
      }
      addln_k<<<BT / 4, 256, 0, stream>>>(X, nullptr, T5, ln2g + (size_t)l * CC,
                                          ln2b + (size_t)l * CC, xlen, 1);
    }

    proj_k<<<gP, 256, 0, stream>>>(X, projw, projb, xlen, out);
  }

  pack_xbct_k<<<dim3(CC / 32, TT / 32, BB), 256, 0, stream>>>(X, out);
  pack_mask_k<<<(BB * TT) / 256, 256, 0, stream>>>(xlen, out);
}